// Round 1
// baseline (3549.964 us; speedup 1.0000x reference)
//
#include <hip/hip_runtime.h>
#include <math.h>

// Problem constants
#define BB 8
#define SS 512
#define DD 768
#define HH 12
#define LL 12
#define DFF 3072
#define VV 40478
#define MM (BB*SS)   // 4096 rows

typedef _Float16 half8 __attribute__((ext_vector_type(8)));
typedef _Float16 half4 __attribute__((ext_vector_type(4)));
typedef float floatx4 __attribute__((ext_vector_type(4)));

// async global->LDS, 16B per lane, LDS dest = wave base + lane*16 (linear)
#define GLDS(gptr, lptr) \
    __builtin_amdgcn_global_load_lds( \
        (const __attribute__((address_space(1))) void*)(gptr), \
        (__attribute__((address_space(3))) void*)(lptr), 16, 0, 0)

// ---------------------------------------------------------------------------
// Embedding: x[b,s,:] = we[tok[b,s],:] + we[V+s,:]  (fp32 + fp16 mirror)
// ---------------------------------------------------------------------------
__global__ __launch_bounds__(256) void embed_kernel(
    const int* __restrict__ tokens, const float* __restrict__ we,
    float* __restrict__ x, _Float16* __restrict__ x16)
{
    int i = blockIdx.x;
    int s = i & (SS - 1);
    int tok = tokens[i];
    const float* wt = we + (size_t)tok * DD;
    const float* wp = we + (size_t)(VV + s) * DD;
    float* xr = x + (size_t)i * DD;
    _Float16* hr = x16 + (size_t)i * DD;
    for (int d = threadIdx.x; d < DD; d += 256) {
        float v = wt[d] + wp[d];
        xr[d] = v;
        hr[d] = (_Float16)v;
    }
}

// ---------------------------------------------------------------------------
// Weight convert: W fp32 [K][N] -> Wt fp16 [N][K] (transpose), 64x64 tiles.
// Makes GEMM B staging identical to A staging (contiguous 16B k-chunks).
// ---------------------------------------------------------------------------
__global__ __launch_bounds__(256) void convw_kernel(
    const float* __restrict__ W, _Float16* __restrict__ Wt, int K, int N)
{
    __shared__ float tile[64][65];
    const int n0 = blockIdx.x * 64, k0 = blockIdx.y * 64;
    const int t = threadIdx.x;
    const int c  = t & 63;
    const int r4 = t >> 6;           // 0..3
#pragma unroll
    for (int rr = 0; rr < 64; rr += 4)
        tile[rr + r4][c] = W[(size_t)(k0 + rr + r4) * N + n0 + c];
    __syncthreads();
#pragma unroll
    for (int nn = 0; nn < 64; nn += 4) {
        int n = nn + r4;
        Wt[(size_t)(n0 + n) * K + k0 + c] = (_Float16)tile[c][n];
    }
}

// ---------------------------------------------------------------------------
// fp16-MFMA GEMM: A fp16 [M][K], Bt fp16 [N][K]. 128x128 tile, BK=32,
// 256 threads (4 waves, 64x64 each). Both tiles staged with
// global_load_lds width=16 into fragment-order LDS (chunk = tid, linear).
// Epilogues: BIAS_RES (fp32 C=acc+bias+resid), BIAS_GELU (fp16 out),
// QKV (fp16 q scaled, k, transposed vT).
// ---------------------------------------------------------------------------
#define EPI_BIAS_RES 1
#define EPI_BIAS_GELU 2
#define EPI_QKV 3

template<int EPI>
__global__ __launch_bounds__(256) void gemm_h_kernel(
    const _Float16* __restrict__ A, const _Float16* __restrict__ Bt,
    const float* __restrict__ bias, const float* __restrict__ resid,
    float* __restrict__ C, _Float16* __restrict__ h16o,
    _Float16* __restrict__ k16o, _Float16* __restrict__ vTo,
    int M, int N, int K)
{
    __shared__ _Float16 As[4096];   // 128 rows x 32 k, chunk order
    __shared__ _Float16 Bs[4096];   // 128 cols x 32 k, chunk order

    const int tid  = threadIdx.x;
    const int lane = tid & 63;
    const int wave = tid >> 6;
    const int row0 = blockIdx.y * 128, col0 = blockIdx.x * 128;

    // staging: thread's (row, kchunk) chosen so LDS chunk index == tid
    const int srow = ((tid >> 6) << 4) + (tid & 15);   // 0..63
    const int skc  = (tid >> 4) & 3;                   // kchunk 0..3
    const _Float16* aptr0 = A  + (size_t)(row0 + srow) * K      + skc * 8;
    const _Float16* aptr1 = A  + (size_t)(row0 + 64 + srow) * K + skc * 8;
    const _Float16* bptr0 = Bt + (size_t)(col0 + srow) * K      + skc * 8;
    const _Float16* bptr1 = Bt + (size_t)(col0 + 64 + srow) * K + skc * 8;

    const int wm = (wave >> 1) << 2;
    const int wn = (wave & 1) << 2;

    floatx4 acc[4][4] = {};

    for (int kk = 0; kk < K; kk += 32) {
        __syncthreads();                    // prev-iter LDS fully consumed
        GLDS(aptr0, As + tid * 8);
        GLDS(aptr1, As + 2048 + tid * 8);
        GLDS(bptr0, Bs + tid * 8);
        GLDS(bptr1, Bs + 2048 + tid * 8);
        aptr0 += 32; aptr1 += 32; bptr0 += 32; bptr1 += 32;
        __syncthreads();                    // vmcnt(0) drain + barrier

        half8 af[4], bf[4];
#pragma unroll
        for (int i = 0; i < 4; ++i) af[i] = *(const half8*)&As[((wm + i) * 64 + lane) * 8];
#pragma unroll
        for (int i = 0; i < 4; ++i) bf[i] = *(const half8*)&Bs[((wn + i) * 64 + lane) * 8];
#pragma unroll
        for (int i = 0; i < 4; ++i)
#pragma unroll
            for (int j = 0; j < 4; ++j)
                acc[i][j] = __builtin_amdgcn_mfma_f32_16x16x32_f16(
                    af[i], bf[j], acc[i][j], 0, 0, 0);
    }

    // Epilogue. C/D layout: col = lane&15, row = (lane>>4)*4 + reg.
    if (EPI == EPI_QKV) {
        const int part = col0 / 768;   // 0=q, 1=k, 2=v (tile never spans parts)
#pragma unroll
        for (int i = 0; i < 4; ++i) {
            int rowb = row0 + ((wm + i) << 4) + ((lane >> 4) << 2);
            int bidx = rowb >> 9;
            int s0   = rowb & 511;
#pragma unroll
            for (int j = 0; j < 4; ++j) {
                int col = col0 + ((wn + j) << 4) + (lane & 15);
                float bsv = bias[col];
                int hh = (col >> 6) % 12;
                int dd = col & 63;
                size_t hb = ((size_t)(bidx * 12 + hh)) << 15;  // *512*64
                if (part == 0) {
#pragma unroll
                    for (int r = 0; r < 4; ++r)
                        h16o[hb + (size_t)(s0 + r) * 64 + dd] =
                            (_Float16)((acc[i][j][r] + bsv) * 0.125f);
                } else if (part == 1) {
#pragma unroll
                    for (int r = 0; r < 4; ++r)
                        k16o[hb + (size_t)(s0 + r) * 64 + dd] =
                            (_Float16)(acc[i][j][r] + bsv);
                } else {
                    half4 pk;
#pragma unroll
                    for (int r = 0; r < 4; ++r)
                        pk[r] = (_Float16)(acc[i][j][r] + bsv);
                    *(half4*)&vTo[hb + (size_t)dd * 512 + s0] = pk;
                }
            }
        }
    } else {
#pragma unroll
        for (int i = 0; i < 4; ++i) {
            int rowb = row0 + ((wm + i) << 4) + ((lane >> 4) << 2);
#pragma unroll
            for (int j = 0; j < 4; ++j) {
                int col = col0 + ((wn + j) << 4) + (lane & 15);
                float bsv = bias[col];
#pragma unroll
                for (int r = 0; r < 4; ++r) {
                    int row = rowb + r;
                    float v = acc[i][j][r] + bsv;
                    if (EPI == EPI_BIAS_RES) {
                        v += resid[(size_t)row * N + col];
                        C[(size_t)row * N + col] = v;
                    }
                    if (EPI == EPI_BIAS_GELU) {
                        float u = v;
                        v = 0.5f * u * (1.0f + tanhf(0.7978845608028654f * (u + 0.044715f * u * u * u)));
                        h16o[(size_t)row * N + col] = (_Float16)v;
                    }
                }
            }
        }
    }
}

// ---------------------------------------------------------------------------
// MFMA flash attention. Block = (q-tile 64, head, batch); 4 waves x 16 q-rows.
// q16 pre-scaled by 1/8. k16: [b,h,s,d]. vT16: [b,h,d,s]. Out fp16 attnb16.
// LDS strides padded (72 f16 / 68 f32) -> all b128 patterns conflict-free.
// ---------------------------------------------------------------------------
__global__ __launch_bounds__(256) void attn_kernel(
    const _Float16* __restrict__ q16, const _Float16* __restrict__ k16,
    const _Float16* __restrict__ vT16, _Float16* __restrict__ attnb)
{
    const int qt = 7 - blockIdx.x;   // biggest q-tiles first
    const int h  = blockIdx.y;
    const int b  = blockIdx.z;
    const int tid  = threadIdx.x;
    const int lane = tid & 63;
    const int wave = tid >> 6;
    const int quad = lane >> 4;
    const int l15  = lane & 15;
    const int wq   = wave << 4;      // wave's q-row base in tile

    __shared__ _Float16 Kt[64 * 72];
    __shared__ _Float16 Vt[64 * 72];   // [d][key]
    __shared__ _Float16 Ps[64 * 72];
    __shared__ float    Ss[64 * 68];
    __shared__ float mS[64], lS[64], aS[64];

    const size_t headbase = ((size_t)(b * HH + h)) << 15;   // *512*64
    const int q0 = qt * 64;

    // Q fragments in registers for the whole kernel (A-operand layout)
    half8 qf0, qf1;
    {
        const _Float16* qp = q16 + headbase + (size_t)(q0 + wq + l15) * 64 + quad * 8;
        qf0 = *(const half8*)qp;
        qf1 = *(const half8*)(qp + 32);
    }
    if (tid < 64) { mS[tid] = -1e30f; lS[tid] = 0.f; }

    floatx4 o[4] = {};

    for (int kt = 0; kt <= qt; ++kt) {
        // --- stage K tile [key][d] and V^T tile [d][key] ---
        {
            int r = tid >> 2;
            int c = (tid & 3) << 4;
            const _Float16* kp = k16 + headbase + (size_t)(kt * 64 + r) * 64 + c;
            half8 k0 = *(const half8*)kp;
            half8 k1 = *(const half8*)(kp + 8);
            const _Float16* vp = vT16 + headbase + (size_t)r * 512 + kt * 64 + c;
            half8 v0 = *(const half8*)vp;
            half8 v1 = *(const half8*)(vp + 8);
            __syncthreads();   // previous iteration fully consumed LDS
            *(half8*)&Kt[r * 72 + c]     = k0;
            *(half8*)&Kt[r * 72 + c + 8] = k1;
            *(half8*)&Vt[r * 72 + c]     = v0;
            *(half8*)&Vt[r * 72 + c + 8] = v1;
        }
        __syncthreads();

        // --- S = Q K^T : 4 key-subtiles x 2 MFMA ---
        floatx4 s4[4];
#pragma unroll
        for (int t4 = 0; t4 < 4; ++t4) {
            half8 kf0 = *(const half8*)&Kt[(t4 * 16 + l15) * 72 + quad * 8];
            half8 kf1 = *(const half8*)&Kt[(t4 * 16 + l15) * 72 + quad * 8 + 32];
            floatx4 a = {};
            a = __builtin_amdgcn_mfma_f32_16x16x32_f16(qf0, kf0, a, 0, 0, 0);
            a = __builtin_amdgcn_mfma_f32_16x16x32_f16(qf1, kf1, a, 0, 0, 0);
            s4[t4] = a;
        }

        // --- causal mask on diagonal tile ---
        if (kt == qt) {
#pragma unroll
            for (int t4 = 0; t4 < 4; ++t4) {
                int kc = t4 * 16 + l15;
#pragma unroll
                for (int r = 0; r < 4; ++r)
                    if (kc > wq + quad * 4 + r) s4[t4][r] = -1e30f;
            }
        }

        // --- scores to LDS (C-layout scatter, conflict-free) ---
#pragma unroll
        for (int t4 = 0; t4 < 4; ++t4)
#pragma unroll
            for (int r = 0; r < 4; ++r)
                Ss[(wq + quad * 4 + r) * 68 + t4 * 16 + l15] = s4[t4][r];
        __syncthreads();

        // --- online softmax: 4 lanes per row, 16 cols each ---
        {
            int rr = tid >> 2, sub = tid & 3;
            float4 p0 = *(const float4*)&Ss[rr * 68 + sub * 16 + 0];
            float4 p1 = *(const float4*)&Ss[rr * 68 + sub * 16 + 4];
            float4 p2 = *(const float4*)&Ss[rr * 68 + sub * 16 + 8];
            float4 p3 = *(const float4*)&Ss[rr * 68 + sub * 16 + 12];
            float tmax = fmaxf(fmaxf(fmaxf(p0.x, p0.y), fmaxf(p0.z, p0.w)),
                         fmaxf(fmaxf(fmaxf(p1.x, p1.y), fmaxf(p1.z, p1.w)),
                         fmaxf(fmaxf(fmaxf(p2.x, p2.y), fmaxf(p2.z, p2.w)),
                               fmaxf(fmaxf(p3.x, p3.y), fmaxf(p3.z, p3.w)))));
            tmax = fmaxf(tmax, __shfl_xor(tmax, 1));
            tmax = fmaxf(tmax, __shfl_xor(tmax, 2));
            float mold = mS[rr];
            float mnew = fmaxf(mold, tmax);
            p0.x = __expf(p0.x - mnew); p0.y = __expf(p0.y - mnew);
            p0.z = __expf(p0.z - mnew); p0.w = __expf(p0.w - mnew);
            p1.x = __expf(p1.x - mnew); p1.y = __expf(p1.y - mnew);
            p1.z = __expf(p1.z - mnew); p1.w = __expf(p1.w - mnew);
            p2.x = __expf(p2.x - mnew); p2.y = __expf(p2.y - mnew);
            p2.z = __expf(p2.z - mnew); p2.w = __expf(p2.w - mnew);
            p3.x = __expf(p3.x - mnew); p3.y = __expf(p3.y - mnew);
            p3.z = __expf(p3.z - mnew); p3.w = __expf(p3.w - mnew);
            float sum = p0.x + p0.y + p0.z + p0.w + p1.x + p1.y + p1.z + p1.w
                      + p2.x + p2.y + p2.z + p2.w + p3.x + p3.y + p3.z + p3.w;
            sum += __shfl_xor(sum, 1);
            sum += __shfl_xor(sum, 2);
            half8 ph0, ph1;
            ph0[0] = (_Float16)p0.x; ph0[1] = (_Float16)p0.y;
            ph0[2] = (_Float16)p0.z; ph0[3] = (_Float16)p0.w;
            ph0[4] = (_Float16)p1.x; ph0[5] = (_Float16)p1.y;
            ph0[6] = (_Float16)p1.z; ph0[7] = (_Float16)p1.w;
            ph1[0] = (_Float16)p2.x; ph1[1] = (_Float16)p2.y;
            ph1[2] = (_Float16)p2.z; ph1[3] = (_Float16)p2.w;
            ph1[4] = (_Float16)p3.x; ph1[5] = (_Float16)p3.y;
            ph1[6] = (_Float16)p3.z; ph1[7] = (_Float16)p3.w;
            *(half8*)&Ps[rr * 72 + sub * 16]     = ph0;
            *(half8*)&Ps[rr * 72 + sub * 16 + 8] = ph1;
            if (sub == 0) {
                float al = __expf(mold - mnew);
                aS[rr] = al;
                mS[rr] = mnew;
                lS[rr] = lS[rr] * al + sum;
            }
        }
        __syncthreads();

        // --- O = O*alpha + P @ V ---
        {
            float al[4];
#pragma unroll
            for (int r = 0; r < 4; ++r) al[r] = aS[wq + quad * 4 + r];
#pragma unroll
            for (int dt = 0; dt < 4; ++dt)
#pragma unroll
                for (int r = 0; r < 4; ++r) o[dt][r] *= al[r];

            half8 pf0 = *(const half8*)&Ps[(wq + l15) * 72 + quad * 8];
            half8 pf1 = *(const half8*)&Ps[(wq + l15) * 72 + quad * 8 + 32];
#pragma unroll
            for (int dt = 0; dt < 4; ++dt) {
                half8 vf0 = *(const half8*)&Vt[(dt * 16 + l15) * 72 + quad * 8];
                half8 vf1 = *(const half8*)&Vt[(dt * 16 + l15) * 72 + quad * 8 + 32];
                o[dt] = __builtin_amdgcn_mfma_f32_16x16x32_f16(pf0, vf0, o[dt], 0, 0, 0);
                o[dt] = __builtin_amdgcn_mfma_f32_16x16x32_f16(pf1, vf1, o[dt], 0, 0, 0);
            }
        }
    }

    // --- finalize: O / l, write fp16 [token][768] ---
    float inv[4];
#pragma unroll
    for (int r = 0; r < 4; ++r) inv[r] = 1.0f / lS[wq + quad * 4 + r];
#pragma unroll
    for (int dt = 0; dt < 4; ++dt) {
        int col = h * 64 + dt * 16 + l15;
#pragma unroll
        for (int r = 0; r < 4; ++r) {
            int row = b * SS + q0 + wq + quad * 4 + r;
            attnb[(size_t)row * DD + col] = (_Float16)(o[dt][r] * inv[r]);
        }
    }
}

// ---------------------------------------------------------------------------
// LayerNorm over last dim (768). One block per row; in-place safe.
// Optional fp16 mirror output for next GEMM's A operand.
// ---------------------------------------------------------------------------
__global__ __launch_bounds__(256) void ln_kernel(
    const float* __restrict__ in, const float* __restrict__ gam,
    const float* __restrict__ bet, float* __restrict__ out,
    _Float16* __restrict__ out16)
{
    int row = blockIdx.x;
    int tid = threadIdx.x;
    const float* p = in + (size_t)row * DD;
    float v0 = p[tid], v1 = p[tid + 256], v2 = p[tid + 512];

    __shared__ float red[256];
    red[tid] = v0 + v1 + v2;
    __syncthreads();
    for (int off = 128; off > 0; off >>= 1) {
        if (tid < off) red[tid] += red[tid + off];
        __syncthreads();
    }
    float mean = red[0] * (1.0f / DD);
    __syncthreads();

    float d0 = v0 - mean, d1 = v1 - mean, d2 = v2 - mean;
    red[tid] = d0 * d0 + d1 * d1 + d2 * d2;
    __syncthreads();
    for (int off = 128; off > 0; off >>= 1) {
        if (tid < off) red[tid] += red[tid + off];
        __syncthreads();
    }
    float rstd = rsqrtf(red[0] * (1.0f / DD) + 1e-5f);

    float* o = out + (size_t)row * DD;
    float r0 = gam[tid]       * (d0 * rstd) + bet[tid];
    float r1 = gam[tid + 256] * (d1 * rstd) + bet[tid + 256];
    float r2 = gam[tid + 512] * (d2 * rstd) + bet[tid + 512];
    o[tid] = r0; o[tid + 256] = r1; o[tid + 512] = r2;
    if (out16) {
        _Float16* oh = out16 + (size_t)row * DD;
        oh[tid] = (_Float16)r0; oh[tid + 256] = (_Float16)r1; oh[tid + 512] = (_Float16)r2;
    }
}

// ---------------------------------------------------------------------------
extern "C" void kernel_launch(void* const* d_in, const int* in_sizes, int n_in,
                              void* d_out, int out_size, void* d_ws, size_t ws_size,
                              hipStream_t stream)
{
    const int*   tokens = (const int*)d_in[0];
    const float* we     = (const float*)d_in[1];
    const float* wqkv   = (const float*)d_in[2];
    const float* bqkv   = (const float*)d_in[3];
    const float* wproj  = (const float*)d_in[4];
    const float* bproj  = (const float*)d_in[5];
    const float* g1     = (const float*)d_in[6];
    const float* b1     = (const float*)d_in[7];
    const float* wfc    = (const float*)d_in[8];
    const float* bfc    = (const float*)d_in[9];
    const float* wpr    = (const float*)d_in[10];
    const float* bpr    = (const float*)d_in[11];
    const float* g2     = (const float*)d_in[12];
    const float* b2     = (const float*)d_in[13];
    float* out = (float*)d_out;

    // Workspace (67.6 MB):
    //   x f32 (12.6M) | n f32 (12.6M) | x16 (6.3M) | n16 (6.3M) |
    //   WBUF fp16 weights, per-GEMM reuse (4.7M) |
    //   BIG (25.2M union): q16,k16,vT16 (18.9M) + attnb16 (6.3M tail) ;
    //                      t f32 (12.6M head, after q/k dead) ; m16 (whole)
    float* x   = (float*)d_ws;
    float* n   = x + (size_t)MM * DD;
    _Float16* x16  = (_Float16*)(n + (size_t)MM * DD);
    _Float16* n16  = x16 + (size_t)MM * DD;
    _Float16* WBUF = n16 + (size_t)MM * DD;          // 768*3072 halves max
    _Float16* BIG  = WBUF + (size_t)DD * DFF;
    _Float16* q16  = BIG;
    _Float16* k16  = q16 + (size_t)MM * DD;
    _Float16* vT16 = k16 + (size_t)MM * DD;
    _Float16* attnb16 = vT16 + (size_t)MM * DD;      // offset 9.44M halves
    float*    t   = (float*)BIG;                     // 12.6MB head (q16+k16 dead)
    _Float16* m16 = BIG;                             // whole BIG (FC1->FC2)

    embed_kernel<<<dim3(MM), 256, 0, stream>>>(tokens, we, x, x16);

    for (int l = 0; l < LL; ++l) {
        // QKV: convert weights, then fp16 GEMM -> q/k/vT buffers
        convw_kernel<<<dim3(2304 / 64, DD / 64), 256, 0, stream>>>(
            wqkv + (size_t)l * DD * 2304, WBUF, DD, 2304);
        gemm_h_kernel<EPI_QKV><<<dim3(2304 / 128, MM / 128), 256, 0, stream>>>(
            x16, WBUF, bqkv + (size_t)l * 2304, nullptr, nullptr,
            q16, k16, vT16, MM, 2304, DD);
        // MFMA flash attention -> fp16 attnb
        attn_kernel<<<dim3(SS / 64, HH, BB), 256, 0, stream>>>(q16, k16, vT16, attnb16);
        // Output projection + residual(x) -> t fp32
        convw_kernel<<<dim3(DD / 64, DD / 64), 256, 0, stream>>>(
            wproj + (size_t)l * DD * DD, WBUF, DD, DD);
        gemm_h_kernel<EPI_BIAS_RES><<<dim3(DD / 128, MM / 128), 256, 0, stream>>>(
            attnb16, WBUF, bproj + (size_t)l * DD,
            x, t, nullptr, nullptr, nullptr, MM, DD, DD);
        // LN1 -> n fp32 + n16
        ln_kernel<<<dim3(MM), 256, 0, stream>>>(t, g1 + (size_t)l * DD,
                                                b1 + (size_t)l * DD, n, n16);
        // FC + GELU -> m16 fp16
        convw_kernel<<<dim3(DFF / 64, DD / 64), 256, 0, stream>>>(
            wfc + (size_t)l * DD * DFF, WBUF, DD, DFF);
        gemm_h_kernel<EPI_BIAS_GELU><<<dim3(DFF / 128, MM / 128), 256, 0, stream>>>(
            n16, WBUF, bfc + (size_t)l * DFF, nullptr, nullptr,
            m16, nullptr, nullptr, MM, DFF, DD);
        // FC2 + residual(n) -> x fp32
        convw_kernel<<<dim3(DD / 64, DFF / 64), 256, 0, stream>>>(
            wpr + (size_t)l * DFF * DD, WBUF, DFF, DD);
        gemm_h_kernel<EPI_BIAS_RES><<<dim3(DD / 128, MM / 128), 256, 0, stream>>>(
            m16, WBUF, bpr + (size_t)l * DD,
            n, x, nullptr, nullptr, nullptr, MM, DD, DFF);
        // LN2 (in-place on x; last layer writes d_out, no fp16 mirror needed)
        ln_kernel<<<dim3(MM), 256, 0, stream>>>(x, g2 + (size_t)l * DD,
                                                b2 + (size_t)l * DD,
                                                (l == LL - 1) ? out : x,
                                                (l == LL - 1) ? nullptr : x16);
    }
}

// Round 2
// 3301.056 us; speedup vs baseline: 1.0754x; 1.0754x over previous
//
#include <hip/hip_runtime.h>
#include <math.h>

// Problem constants
#define BB 8
#define SS 512
#define DD 768
#define HH 12
#define LL 12
#define DFF 3072
#define VV 40478
#define MM (BB*SS)   // 4096 rows

typedef _Float16 half8 __attribute__((ext_vector_type(8)));
typedef _Float16 half4 __attribute__((ext_vector_type(4)));
typedef float floatx4 __attribute__((ext_vector_type(4)));

// async global->LDS, 16B per lane, LDS dest = wave base + lane*16 (linear)
#define GLDS(gptr, lptr) \
    __builtin_amdgcn_global_load_lds( \
        (const __attribute__((address_space(1))) void*)(gptr), \
        (__attribute__((address_space(3))) void*)(lptr), 16, 0, 0)

// ---------------------------------------------------------------------------
// Embedding: x[b,s,:] = we[tok[b,s],:] + we[V+s,:]  (fp32 + fp16 mirror)
// ---------------------------------------------------------------------------
__global__ __launch_bounds__(256) void embed_kernel(
    const int* __restrict__ tokens, const float* __restrict__ we,
    float* __restrict__ x, _Float16* __restrict__ x16)
{
    int i = blockIdx.x;
    int s = i & (SS - 1);
    int tok = tokens[i];
    const float* wt = we + (size_t)tok * DD;
    const float* wp = we + (size_t)(VV + s) * DD;
    float* xr = x + (size_t)i * DD;
    _Float16* hr = x16 + (size_t)i * DD;
    for (int d = threadIdx.x; d < DD; d += 256) {
        float v = wt[d] + wp[d];
        xr[d] = v;
        hr[d] = (_Float16)v;
    }
}

// ---------------------------------------------------------------------------
// Weight convert: W fp32 [K][N] -> Wt fp16 [N][K] (transpose), 64x64 tiles.
// convw4_kernel: wqkv + wproj + wfc of one layer in a single dispatch.
// convw_kernel: single matrix (used for wpr, overlapping WBUF reuse).
// ---------------------------------------------------------------------------
__device__ __forceinline__ void convw_tile(
    const float* __restrict__ W, _Float16* __restrict__ Wt,
    int K, int N, int n0, int k0)
{
    __shared__ float tile[64][65];
    const int t = threadIdx.x;
    const int c  = t & 63;
    const int r4 = t >> 6;           // 0..3
#pragma unroll
    for (int rr = 0; rr < 64; rr += 4)
        tile[rr + r4][c] = W[(size_t)(k0 + rr + r4) * N + n0 + c];
    __syncthreads();
#pragma unroll
    for (int nn = 0; nn < 64; nn += 4) {
        int n = nn + r4;
        Wt[(size_t)(n0 + n) * K + k0 + c] = (_Float16)tile[c][n];
    }
}

__global__ __launch_bounds__(256) void convw_kernel(
    const float* __restrict__ W, _Float16* __restrict__ Wt, int K, int N)
{
    const int ntx = N >> 6;
    const int b = blockIdx.x;
    convw_tile(W, Wt, K, N, (b % ntx) * 64, (b / ntx) * 64);
}

__global__ __launch_bounds__(256) void convw3_kernel(
    const float* __restrict__ w0, const float* __restrict__ w1,
    const float* __restrict__ w2,
    _Float16* __restrict__ o0, _Float16* __restrict__ o1,
    _Float16* __restrict__ o2)
{
    int b = blockIdx.x;
    const float* W; _Float16* Wt; int N, tb;
    if (b < 432)       { W = w0; Wt = o0; N = 2304; tb = b; }
    else if (b < 576)  { W = w1; Wt = o1; N = 768;  tb = b - 432; }
    else               { W = w2; Wt = o2; N = 3072; tb = b - 576; }
    const int ntx = N >> 6;
    convw_tile(W, Wt, 768, N, (tb % ntx) * 64, (tb / ntx) * 64);
}

// ---------------------------------------------------------------------------
// fp16-MFMA GEMM: A fp16 [M][K], Bt fp16 [N][K]. 128x128 tile, BK=32,
// 256 threads (4 waves, 64x64 each). Both tiles staged with
// global_load_lds width=16 into fragment-order LDS (chunk = tid, linear).
// Double-buffered LDS + counted vmcnt(4) prefetch (T3-lite) + XCD swizzle.
// Epilogues: BIAS_RES (fp32 C=acc+bias+resid), BIAS_GELU (fp16 out),
// QKV (fp16 q scaled, k, transposed vT).
// ---------------------------------------------------------------------------
#define EPI_BIAS_RES 1
#define EPI_BIAS_GELU 2
#define EPI_QKV 3

template<int EPI>
__global__ __launch_bounds__(256) void gemm_h_kernel(
    const _Float16* __restrict__ A, const _Float16* __restrict__ Bt,
    const float* __restrict__ bias, const float* __restrict__ resid,
    float* __restrict__ C, _Float16* __restrict__ h16o,
    _Float16* __restrict__ k16o, _Float16* __restrict__ vTo,
    int M, int N, int K)
{
    __shared__ _Float16 As[2][4096];   // 128 rows x 32 k, chunk order
    __shared__ _Float16 Bs[2][4096];   // 128 cols x 32 k, chunk order

    const int tid  = threadIdx.x;
    const int lane = tid & 63;
    const int wave = tid >> 6;

    // XCD-aware bijective swizzle (all grids are multiples of 8 blocks):
    // consecutive logical tiles land on the same XCD -> A-panel L2 reuse.
    const int gx  = gridDim.x;
    const int lb  = blockIdx.y * gx + blockIdx.x;
    const int q8  = (gx * gridDim.y) >> 3;
    const int swz = (lb & 7) * q8 + (lb >> 3);
    const int row0 = (swz / gx) * 128, col0 = (swz % gx) * 128;

    // staging: thread's (row, kchunk) chosen so LDS chunk index == tid
    const int srow = ((tid >> 6) << 4) + (tid & 15);   // 0..63
    const int skc  = (tid >> 4) & 3;                   // kchunk 0..3
    const _Float16* aptr0 = A  + (size_t)(row0 + srow) * K      + skc * 8;
    const _Float16* aptr1 = A  + (size_t)(row0 + 64 + srow) * K + skc * 8;
    const _Float16* bptr0 = Bt + (size_t)(col0 + srow) * K      + skc * 8;
    const _Float16* bptr1 = Bt + (size_t)(col0 + 64 + srow) * K + skc * 8;

    const int wm = (wave >> 1) << 2;
    const int wn = (wave & 1) << 2;

    floatx4 acc[4][4] = {};

    const int nk = K >> 5;

    // prologue: stage tile 0 into buffer 0
    GLDS(aptr0, &As[0][tid * 8]);
    GLDS(aptr1, &As[0][2048 + tid * 8]);
    GLDS(bptr0, &Bs[0][tid * 8]);
    GLDS(bptr1, &Bs[0][2048 + tid * 8]);
    aptr0 += 32; aptr1 += 32; bptr0 += 32; bptr1 += 32;

    for (int t = 0; t < nk; ++t) {
        const _Float16* Asc = As[t & 1];
        const _Float16* Bsc = Bs[t & 1];
        if (t + 1 < nk) {
            _Float16* Asn = As[(t + 1) & 1];
            _Float16* Bsn = Bs[(t + 1) & 1];
            GLDS(aptr0, Asn + tid * 8);
            GLDS(aptr1, Asn + 2048 + tid * 8);
            GLDS(bptr0, Bsn + tid * 8);
            GLDS(bptr1, Bsn + 2048 + tid * 8);
            aptr0 += 32; aptr1 += 32; bptr0 += 32; bptr1 += 32;
            // wait tile t's 4 loads only; tile t+1's stay in flight
            asm volatile("s_waitcnt vmcnt(4)" ::: "memory");
        } else {
            asm volatile("s_waitcnt vmcnt(0)" ::: "memory");
        }
        __builtin_amdgcn_s_barrier();
        asm volatile("" ::: "memory");

        half8 af[4], bf[4];
#pragma unroll
        for (int i = 0; i < 4; ++i) af[i] = *(const half8*)&Asc[((wm + i) * 64 + lane) * 8];
#pragma unroll
        for (int i = 0; i < 4; ++i) bf[i] = *(const half8*)&Bsc[((wn + i) * 64 + lane) * 8];
#pragma unroll
        for (int i = 0; i < 4; ++i)
#pragma unroll
            for (int j = 0; j < 4; ++j)
                acc[i][j] = __builtin_amdgcn_mfma_f32_16x16x32_f16(
                    af[i], bf[j], acc[i][j], 0, 0, 0);

        asm volatile("" ::: "memory");
        __builtin_amdgcn_s_barrier();   // readers of buf[t&1] done before overwrite
    }

    // Epilogue. C/D layout: col = lane&15, row = (lane>>4)*4 + reg.
    if (EPI == EPI_QKV) {
        const int part = col0 / 768;   // 0=q, 1=k, 2=v (tile never spans parts)
#pragma unroll
        for (int i = 0; i < 4; ++i) {
            int rowb = row0 + ((wm + i) << 4) + ((lane >> 4) << 2);
            int bidx = rowb >> 9;
            int s0   = rowb & 511;
#pragma unroll
            for (int j = 0; j < 4; ++j) {
                int col = col0 + ((wn + j) << 4) + (lane & 15);
                float bsv = bias[col];
                int hh = (col >> 6) % 12;
                int dd = col & 63;
                size_t hb = ((size_t)(bidx * 12 + hh)) << 15;  // *512*64
                if (part == 0) {
#pragma unroll
                    for (int r = 0; r < 4; ++r)
                        h16o[hb + (size_t)(s0 + r) * 64 + dd] =
                            (_Float16)((acc[i][j][r] + bsv) * 0.125f);
                } else if (part == 1) {
#pragma unroll
                    for (int r = 0; r < 4; ++r)
                        k16o[hb + (size_t)(s0 + r) * 64 + dd] =
                            (_Float16)(acc[i][j][r] + bsv);
                } else {
                    half4 pk;
#pragma unroll
                    for (int r = 0; r < 4; ++r)
                        pk[r] = (_Float16)(acc[i][j][r] + bsv);
                    *(half4*)&vTo[hb + (size_t)dd * 512 + s0] = pk;
                }
            }
        }
    } else {
#pragma unroll
        for (int i = 0; i < 4; ++i) {
            int rowb = row0 + ((wm + i) << 4) + ((lane >> 4) << 2);
#pragma unroll
            for (int j = 0; j < 4; ++j) {
                int col = col0 + ((wn + j) << 4) + (lane & 15);
                float bsv = bias[col];
#pragma unroll
                for (int r = 0; r < 4; ++r) {
                    int row = rowb + r;
                    float v = acc[i][j][r] + bsv;
                    if (EPI == EPI_BIAS_RES) {
                        v += resid[(size_t)row * N + col];
                        C[(size_t)row * N + col] = v;
                    }
                    if (EPI == EPI_BIAS_GELU) {
                        float u = v;
                        v = 0.5f * u * (1.0f + tanhf(0.7978845608028654f * (u + 0.044715f * u * u * u)));
                        h16o[(size_t)row * N + col] = (_Float16)v;
                    }
                }
            }
        }
    }
}

// ---------------------------------------------------------------------------
// MFMA flash attention. Block = (q-tile 64, head, batch); 4 waves x 16 q-rows.
// q16 pre-scaled by 1/8. k16: [b,h,s,d]. vT16: [b,h,d,s]. Out fp16 attnb16.
// LDS strides padded (72 f16 / 68 f32) -> all b128 patterns conflict-free.
// ---------------------------------------------------------------------------
__global__ __launch_bounds__(256) void attn_kernel(
    const _Float16* __restrict__ q16, const _Float16* __restrict__ k16,
    const _Float16* __restrict__ vT16, _Float16* __restrict__ attnb)
{
    const int qt = 7 - blockIdx.x;   // biggest q-tiles first
    const int h  = blockIdx.y;
    const int b  = blockIdx.z;
    const int tid  = threadIdx.x;
    const int lane = tid & 63;
    const int wave = tid >> 6;
    const int quad = lane >> 4;
    const int l15  = lane & 15;
    const int wq   = wave << 4;      // wave's q-row base in tile

    __shared__ _Float16 Kt[64 * 72];
    __shared__ _Float16 Vt[64 * 72];   // [d][key]
    __shared__ _Float16 Ps[64 * 72];
    __shared__ float    Ss[64 * 68];
    __shared__ float mS[64], lS[64], aS[64];

    const size_t headbase = ((size_t)(b * HH + h)) << 15;   // *512*64
    const int q0 = qt * 64;

    // Q fragments in registers for the whole kernel (A-operand layout)
    half8 qf0, qf1;
    {
        const _Float16* qp = q16 + headbase + (size_t)(q0 + wq + l15) * 64 + quad * 8;
        qf0 = *(const half8*)qp;
        qf1 = *(const half8*)(qp + 32);
    }
    if (tid < 64) { mS[tid] = -1e30f; lS[tid] = 0.f; }

    floatx4 o[4] = {};

    for (int kt = 0; kt <= qt; ++kt) {
        // --- stage K tile [key][d] and V^T tile [d][key] ---
        {
            int r = tid >> 2;
            int c = (tid & 3) << 4;
            const _Float16* kp = k16 + headbase + (size_t)(kt * 64 + r) * 64 + c;
            half8 k0 = *(const half8*)kp;
            half8 k1 = *(const half8*)(kp + 8);
            const _Float16* vp = vT16 + headbase + (size_t)r * 512 + kt * 64 + c;
            half8 v0 = *(const half8*)vp;
            half8 v1 = *(const half8*)(vp + 8);
            __syncthreads();   // previous iteration fully consumed LDS
            *(half8*)&Kt[r * 72 + c]     = k0;
            *(half8*)&Kt[r * 72 + c + 8] = k1;
            *(half8*)&Vt[r * 72 + c]     = v0;
            *(half8*)&Vt[r * 72 + c + 8] = v1;
        }
        __syncthreads();

        // --- S = Q K^T : 4 key-subtiles x 2 MFMA ---
        floatx4 s4[4];
#pragma unroll
        for (int t4 = 0; t4 < 4; ++t4) {
            half8 kf0 = *(const half8*)&Kt[(t4 * 16 + l15) * 72 + quad * 8];
            half8 kf1 = *(const half8*)&Kt[(t4 * 16 + l15) * 72 + quad * 8 + 32];
            floatx4 a = {};
            a = __builtin_amdgcn_mfma_f32_16x16x32_f16(qf0, kf0, a, 0, 0, 0);
            a = __builtin_amdgcn_mfma_f32_16x16x32_f16(qf1, kf1, a, 0, 0, 0);
            s4[t4] = a;
        }

        // --- causal mask on diagonal tile ---
        if (kt == qt) {
#pragma unroll
            for (int t4 = 0; t4 < 4; ++t4) {
                int kc = t4 * 16 + l15;
#pragma unroll
                for (int r = 0; r < 4; ++r)
                    if (kc > wq + quad * 4 + r) s4[t4][r] = -1e30f;
            }
        }

        // --- scores to LDS (C-layout scatter, conflict-free) ---
#pragma unroll
        for (int t4 = 0; t4 < 4; ++t4)
#pragma unroll
            for (int r = 0; r < 4; ++r)
                Ss[(wq + quad * 4 + r) * 68 + t4 * 16 + l15] = s4[t4][r];
        __syncthreads();

        // --- online softmax: 4 lanes per row, 16 cols each ---
        {
            int rr = tid >> 2, sub = tid & 3;
            float4 p0 = *(const float4*)&Ss[rr * 68 + sub * 16 + 0];
            float4 p1 = *(const float4*)&Ss[rr * 68 + sub * 16 + 4];
            float4 p2 = *(const float4*)&Ss[rr * 68 + sub * 16 + 8];
            float4 p3 = *(const float4*)&Ss[rr * 68 + sub * 16 + 12];
            float tmax = fmaxf(fmaxf(fmaxf(p0.x, p0.y), fmaxf(p0.z, p0.w)),
                         fmaxf(fmaxf(fmaxf(p1.x, p1.y), fmaxf(p1.z, p1.w)),
                         fmaxf(fmaxf(fmaxf(p2.x, p2.y), fmaxf(p2.z, p2.w)),
                               fmaxf(fmaxf(p3.x, p3.y), fmaxf(p3.z, p3.w)))));
            tmax = fmaxf(tmax, __shfl_xor(tmax, 1));
            tmax = fmaxf(tmax, __shfl_xor(tmax, 2));
            float mold = mS[rr];
            float mnew = fmaxf(mold, tmax);
            p0.x = __expf(p0.x - mnew); p0.y = __expf(p0.y - mnew);
            p0.z = __expf(p0.z - mnew); p0.w = __expf(p0.w - mnew);
            p1.x = __expf(p1.x - mnew); p1.y = __expf(p1.y - mnew);
            p1.z = __expf(p1.z - mnew); p1.w = __expf(p1.w - mnew);
            p2.x = __expf(p2.x - mnew); p2.y = __expf(p2.y - mnew);
            p2.z = __expf(p2.z - mnew); p2.w = __expf(p2.w - mnew);
            p3.x = __expf(p3.x - mnew); p3.y = __expf(p3.y - mnew);
            p3.z = __expf(p3.z - mnew); p3.w = __expf(p3.w - mnew);
            float sum = p0.x + p0.y + p0.z + p0.w + p1.x + p1.y + p1.z + p1.w
                      + p2.x + p2.y + p2.z + p2.w + p3.x + p3.y + p3.z + p3.w;
            sum += __shfl_xor(sum, 1);
            sum += __shfl_xor(sum, 2);
            half8 ph0, ph1;
            ph0[0] = (_Float16)p0.x; ph0[1] = (_Float16)p0.y;
            ph0[2] = (_Float16)p0.z; ph0[3] = (_Float16)p0.w;
            ph0[4] = (_Float16)p1.x; ph0[5] = (_Float16)p1.y;
            ph0[6] = (_Float16)p1.z; ph0[7] = (_Float16)p1.w;
            ph1[0] = (_Float16)p2.x; ph1[1] = (_Float16)p2.y;
            ph1[2] = (_Float16)p2.z; ph1[3] = (_Float16)p2.w;
            ph1[4] = (_Float16)p3.x; ph1[5] = (_Float16)p3.y;
            ph1[6] = (_Float16)p3.z; ph1[7] = (_Float16)p3.w;
            *(half8*)&Ps[rr * 72 + sub * 16]     = ph0;
            *(half8*)&Ps[rr * 72 + sub * 16 + 8] = ph1;
            if (sub == 0) {
                float al = __expf(mold - mnew);
                aS[rr] = al;
                mS[rr] = mnew;
                lS[rr] = lS[rr] * al + sum;
            }
        }
        __syncthreads();

        // --- O = O*alpha + P @ V ---
        {
            float al[4];
#pragma unroll
            for (int r = 0; r < 4; ++r) al[r] = aS[wq + quad * 4 + r];
#pragma unroll
            for (int dt = 0; dt < 4; ++dt)
#pragma unroll
                for (int r = 0; r < 4; ++r) o[dt][r] *= al[r];

            half8 pf0 = *(const half8*)&Ps[(wq + l15) * 72 + quad * 8];
            half8 pf1 = *(const half8*)&Ps[(wq + l15) * 72 + quad * 8 + 32];
#pragma unroll
            for (int dt = 0; dt < 4; ++dt) {
                half8 vf0 = *(const half8*)&Vt[(dt * 16 + l15) * 72 + quad * 8];
                half8 vf1 = *(const half8*)&Vt[(dt * 16 + l15) * 72 + quad * 8 + 32];
                o[dt] = __builtin_amdgcn_mfma_f32_16x16x32_f16(pf0, vf0, o[dt], 0, 0, 0);
                o[dt] = __builtin_amdgcn_mfma_f32_16x16x32_f16(pf1, vf1, o[dt], 0, 0, 0);
            }
        }
    }

    // --- finalize: O / l, write fp16 [token][768] ---
    float inv[4];
#pragma unroll
    for (int r = 0; r < 4; ++r) inv[r] = 1.0f / lS[wq + quad * 4 + r];
#pragma unroll
    for (int dt = 0; dt < 4; ++dt) {
        int col = h * 64 + dt * 16 + l15;
#pragma unroll
        for (int r = 0; r < 4; ++r) {
            int row = b * SS + q0 + wq + quad * 4 + r;
            attnb[(size_t)row * DD + col] = (_Float16)(o[dt][r] * inv[r]);
        }
    }
}

// ---------------------------------------------------------------------------
// LayerNorm over last dim (768). One block per row; in-place safe.
// Optional fp16 mirror output for next GEMM's A operand.
// ---------------------------------------------------------------------------
__global__ __launch_bounds__(256) void ln_kernel(
    const float* __restrict__ in, const float* __restrict__ gam,
    const float* __restrict__ bet, float* __restrict__ out,
    _Float16* __restrict__ out16)
{
    int row = blockIdx.x;
    int tid = threadIdx.x;
    const float* p = in + (size_t)row * DD;
    float v0 = p[tid], v1 = p[tid + 256], v2 = p[tid + 512];

    __shared__ float red[256];
    red[tid] = v0 + v1 + v2;
    __syncthreads();
    for (int off = 128; off > 0; off >>= 1) {
        if (tid < off) red[tid] += red[tid + off];
        __syncthreads();
    }
    float mean = red[0] * (1.0f / DD);
    __syncthreads();

    float d0 = v0 - mean, d1 = v1 - mean, d2 = v2 - mean;
    red[tid] = d0 * d0 + d1 * d1 + d2 * d2;
    __syncthreads();
    for (int off = 128; off > 0; off >>= 1) {
        if (tid < off) red[tid] += red[tid + off];
        __syncthreads();
    }
    float rstd = rsqrtf(red[0] * (1.0f / DD) + 1e-5f);

    float* o = out + (size_t)row * DD;
    float r0 = gam[tid]       * (d0 * rstd) + bet[tid];
    float r1 = gam[tid + 256] * (d1 * rstd) + bet[tid + 256];
    float r2 = gam[tid + 512] * (d2 * rstd) + bet[tid + 512];
    o[tid] = r0; o[tid + 256] = r1; o[tid + 512] = r2;
    if (out16) {
        _Float16* oh = out16 + (size_t)row * DD;
        oh[tid] = (_Float16)r0; oh[tid + 256] = (_Float16)r1; oh[tid + 512] = (_Float16)r2;
    }
}

// ---------------------------------------------------------------------------
extern "C" void kernel_launch(void* const* d_in, const int* in_sizes, int n_in,
                              void* d_out, int out_size, void* d_ws, size_t ws_size,
                              hipStream_t stream)
{
    const int*   tokens = (const int*)d_in[0];
    const float* we     = (const float*)d_in[1];
    const float* wqkv   = (const float*)d_in[2];
    const float* bqkv   = (const float*)d_in[3];
    const float* wproj  = (const float*)d_in[4];
    const float* bproj  = (const float*)d_in[5];
    const float* g1     = (const float*)d_in[6];
    const float* b1     = (const float*)d_in[7];
    const float* wfc    = (const float*)d_in[8];
    const float* bfc    = (const float*)d_in[9];
    const float* wpr    = (const float*)d_in[10];
    const float* bpr    = (const float*)d_in[11];
    const float* g2     = (const float*)d_in[12];
    const float* b2     = (const float*)d_in[13];
    float* out = (float*)d_out;

    // Workspace (72.4 MB):
    //   x f32 (12.6M) | n f32 (12.6M) | x16 (6.3M) | n16 (6.3M) |
    //   WBUF fp16 weights (9.44M: qkv_t 1.77M | proj_t 0.59M | fc_t 2.36M;
    //     wpr_t 2.36M halves reuses WBUF base after FC1) |
    //   BIG (25.2M union): q16,k16,vT16 (18.9M) + attnb16 (6.3M tail) ;
    //                      t f32 (12.6M head, after q/k dead) ; m16 (whole)
    float* x   = (float*)d_ws;
    float* n   = x + (size_t)MM * DD;
    _Float16* x16  = (_Float16*)(n + (size_t)MM * DD);
    _Float16* n16  = x16 + (size_t)MM * DD;
    _Float16* WBUF = n16 + (size_t)MM * DD;
    _Float16* wq_t = WBUF;                               // 2304x768
    _Float16* wp_t = wq_t + (size_t)2304 * DD;           // 768x768
    _Float16* wf_t = wp_t + (size_t)DD * DD;             // 3072x768
    _Float16* wr_t = WBUF;                               // 768x3072 (reuse)
    _Float16* BIG  = wf_t + (size_t)DFF * DD;
    _Float16* q16  = BIG;
    _Float16* k16  = q16 + (size_t)MM * DD;
    _Float16* vT16 = k16 + (size_t)MM * DD;
    _Float16* attnb16 = vT16 + (size_t)MM * DD;
    float*    t   = (float*)BIG;
    _Float16* m16 = BIG;

    embed_kernel<<<dim3(MM), 256, 0, stream>>>(tokens, we, x, x16);

    for (int l = 0; l < LL; ++l) {
        // Convert wqkv + wproj + wfc (one dispatch, 1152 tiles)
        convw3_kernel<<<dim3(1152), 256, 0, stream>>>(
            wqkv + (size_t)l * DD * 2304, wproj + (size_t)l * DD * DD,
            wfc + (size_t)l * DD * DFF, wq_t, wp_t, wf_t);
        // QKV projection -> fp16 q/k/vT buffers
        gemm_h_kernel<EPI_QKV><<<dim3(2304 / 128, MM / 128), 256, 0, stream>>>(
            x16, wq_t, bqkv + (size_t)l * 2304, nullptr, nullptr,
            q16, k16, vT16, MM, 2304, DD);
        // MFMA flash attention -> fp16 attnb
        attn_kernel<<<dim3(SS / 64, HH, BB), 256, 0, stream>>>(q16, k16, vT16, attnb16);
        // Output projection + residual(x) -> t fp32
        gemm_h_kernel<EPI_BIAS_RES><<<dim3(DD / 128, MM / 128), 256, 0, stream>>>(
            attnb16, wp_t, bproj + (size_t)l * DD,
            x, t, nullptr, nullptr, nullptr, MM, DD, DD);
        // LN1 -> n fp32 + n16
        ln_kernel<<<dim3(MM), 256, 0, stream>>>(t, g1 + (size_t)l * DD,
                                                b1 + (size_t)l * DD, n, n16);
        // FC + GELU -> m16 fp16
        gemm_h_kernel<EPI_BIAS_GELU><<<dim3(DFF / 128, MM / 128), 256, 0, stream>>>(
            n16, wf_t, bfc + (size_t)l * DFF, nullptr, nullptr,
            m16, nullptr, nullptr, MM, DFF, DD);
        // Convert wpr (reuses WBUF base; qkv/proj/fc weights dead now)
        convw_kernel<<<dim3(576), 256, 0, stream>>>(
            wpr + (size_t)l * DFF * DD, wr_t, DFF, DD);
        // FC2 + residual(n) -> x fp32
        gemm_h_kernel<EPI_BIAS_RES><<<dim3(DD / 128, MM / 128), 256, 0, stream>>>(
            m16, wr_t, bpr + (size_t)l * DD,
            n, x, nullptr, nullptr, nullptr, MM, DD, DFF);
        // LN2 (in-place on x; last layer writes d_out, no fp16 mirror needed)
        ln_kernel<<<dim3(MM), 256, 0, stream>>>(x, g2 + (size_t)l * DD,
                                                b2 + (size_t)l * DD,
                                                (l == LL - 1) ? out : x,
                                                (l == LL - 1) ? nullptr : x16);
    }
}

// Round 3
// 3296.540 us; speedup vs baseline: 1.0769x; 1.0014x over previous
//
#include <hip/hip_runtime.h>
#include <math.h>

// Problem constants
#define BB 8
#define SS 512
#define DD 768
#define HH 12
#define LL 12
#define DFF 3072
#define VV 40478
#define MM (BB*SS)   // 4096 rows

typedef _Float16 half8 __attribute__((ext_vector_type(8)));
typedef _Float16 half4 __attribute__((ext_vector_type(4)));
typedef float floatx4 __attribute__((ext_vector_type(4)));

// async global->LDS, 16B per lane, LDS dest = wave base + lane*16 (linear)
#define GLDS(gptr, lptr) \
    __builtin_amdgcn_global_load_lds( \
        (const __attribute__((address_space(1))) void*)(gptr), \
        (__attribute__((address_space(3))) void*)(lptr), 16, 0, 0)

// ---------------------------------------------------------------------------
// Embedding: x[b,s,:] = we[tok[b,s],:] + we[V+s,:]  (fp32 + fp16 mirror)
// ---------------------------------------------------------------------------
__global__ __launch_bounds__(256) void embed_kernel(
    const int* __restrict__ tokens, const float* __restrict__ we,
    float* __restrict__ x, _Float16* __restrict__ x16)
{
    int i = blockIdx.x;
    int s = i & (SS - 1);
    int tok = tokens[i];
    const float* wt = we + (size_t)tok * DD;
    const float* wp = we + (size_t)(VV + s) * DD;
    float* xr = x + (size_t)i * DD;
    _Float16* hr = x16 + (size_t)i * DD;
    for (int d = threadIdx.x; d < DD; d += 256) {
        float v = wt[d] + wp[d];
        xr[d] = v;
        hr[d] = (_Float16)v;
    }
}

// ---------------------------------------------------------------------------
// Weight convert: W fp32 [K][N] -> Wt fp16 [N][K] (transpose), 64x64 tiles.
// convw3_kernel: wqkv + wproj + wfc of one layer in a single dispatch.
// convw_kernel: single matrix (used for wpr, overlapping WBUF reuse).
// ---------------------------------------------------------------------------
__device__ __forceinline__ void convw_tile(
    const float* __restrict__ W, _Float16* __restrict__ Wt,
    int K, int N, int n0, int k0)
{
    __shared__ float tile[64][65];
    const int t = threadIdx.x;
    const int c  = t & 63;
    const int r4 = t >> 6;           // 0..3
#pragma unroll
    for (int rr = 0; rr < 64; rr += 4)
        tile[rr + r4][c] = W[(size_t)(k0 + rr + r4) * N + n0 + c];
    __syncthreads();
#pragma unroll
    for (int nn = 0; nn < 64; nn += 4) {
        int n = nn + r4;
        Wt[(size_t)(n0 + n) * K + k0 + c] = (_Float16)tile[c][n];
    }
}

__global__ __launch_bounds__(256) void convw_kernel(
    const float* __restrict__ W, _Float16* __restrict__ Wt, int K, int N)
{
    const int ntx = N >> 6;
    const int b = blockIdx.x;
    convw_tile(W, Wt, K, N, (b % ntx) * 64, (b / ntx) * 64);
}

__global__ __launch_bounds__(256) void convw3_kernel(
    const float* __restrict__ w0, const float* __restrict__ w1,
    const float* __restrict__ w2,
    _Float16* __restrict__ o0, _Float16* __restrict__ o1,
    _Float16* __restrict__ o2)
{
    int b = blockIdx.x;
    const float* W; _Float16* Wt; int N, tb;
    if (b < 432)       { W = w0; Wt = o0; N = 2304; tb = b; }
    else if (b < 576)  { W = w1; Wt = o1; N = 768;  tb = b - 432; }
    else               { W = w2; Wt = o2; N = 3072; tb = b - 576; }
    const int ntx = N >> 6;
    convw_tile(W, Wt, 768, N, (tb % ntx) * 64, (tb / ntx) * 64);
}

// ---------------------------------------------------------------------------
// fp16-MFMA GEMM: A fp16 [M][K], Bt fp16 [N][K]. 128x128 tile, BK=32,
// 256 threads (4 waves, 64x64 each). Both tiles staged with
// global_load_lds width=16 into fragment-order LDS (chunk = tid, linear).
// 3-stage pipeline: issue distance 2, steady-state vmcnt(8) -> two tile
// pairs (8 loads/wave) stay in flight across barriers (T3+T4 counted-vmcnt).
// XCD-aware bijective block swizzle for A-panel L2 reuse.
// Epilogues: BIAS_RES (fp32 C=acc+bias+resid), BIAS_GELU (fp16 out),
// QKV (fp16 q scaled, k, transposed vT).
// ---------------------------------------------------------------------------
#define EPI_BIAS_RES 1
#define EPI_BIAS_GELU 2
#define EPI_QKV 3

template<int EPI>
__global__ __launch_bounds__(256) void gemm_h_kernel(
    const _Float16* __restrict__ A, const _Float16* __restrict__ Bt,
    const float* __restrict__ bias, const float* __restrict__ resid,
    float* __restrict__ C, _Float16* __restrict__ h16o,
    _Float16* __restrict__ k16o, _Float16* __restrict__ vTo,
    int M, int N, int K)
{
    __shared__ _Float16 As[3][4096];   // 128 rows x 32 k, chunk order
    __shared__ _Float16 Bs[3][4096];   // 128 cols x 32 k, chunk order

    const int tid  = threadIdx.x;
    const int lane = tid & 63;
    const int wave = tid >> 6;

    // XCD-aware bijective swizzle (all grids are multiples of 8 blocks):
    // consecutive logical tiles land on the same XCD -> A-panel L2 reuse.
    const int gx  = gridDim.x;
    const int lb  = blockIdx.y * gx + blockIdx.x;
    const int q8  = (gx * gridDim.y) >> 3;
    const int swz = (lb & 7) * q8 + (lb >> 3);
    const int row0 = (swz / gx) * 128, col0 = (swz % gx) * 128;

    // staging: thread's (row, kchunk) chosen so LDS chunk index == tid
    const int srow = ((tid >> 6) << 4) + (tid & 15);   // 0..63
    const int skc  = (tid >> 4) & 3;                   // kchunk 0..3
    const _Float16* aptr0 = A  + (size_t)(row0 + srow) * K      + skc * 8;
    const _Float16* aptr1 = A  + (size_t)(row0 + 64 + srow) * K + skc * 8;
    const _Float16* bptr0 = Bt + (size_t)(col0 + srow) * K      + skc * 8;
    const _Float16* bptr1 = Bt + (size_t)(col0 + 64 + srow) * K + skc * 8;

    const int wm = (wave >> 1) << 2;
    const int wn = (wave & 1) << 2;

    floatx4 acc[4][4] = {};

    const int nk = K >> 5;

    // prologue: stage tiles 0 and 1 into buffers 0 and 1
    GLDS(aptr0, &As[0][tid * 8]);
    GLDS(aptr1, &As[0][2048 + tid * 8]);
    GLDS(bptr0, &Bs[0][tid * 8]);
    GLDS(bptr1, &Bs[0][2048 + tid * 8]);
    aptr0 += 32; aptr1 += 32; bptr0 += 32; bptr1 += 32;
    GLDS(aptr0, &As[1][tid * 8]);
    GLDS(aptr1, &As[1][2048 + tid * 8]);
    GLDS(bptr0, &Bs[1][tid * 8]);
    GLDS(bptr1, &Bs[1][2048 + tid * 8]);
    aptr0 += 32; aptr1 += 32; bptr0 += 32; bptr1 += 32;

    int cb = 0;   // compute buffer
    int wb = 2;   // write (stage) buffer

    for (int t = 0; t < nk; ++t) {
        if (t + 2 < nk) {
            // buffer wb's previous contents were consumed at iter t-1;
            // the trailing barrier of iter t-1 makes this overwrite safe.
            GLDS(aptr0, &As[wb][tid * 8]);
            GLDS(aptr1, &As[wb][2048 + tid * 8]);
            GLDS(bptr0, &Bs[wb][tid * 8]);
            GLDS(bptr1, &Bs[wb][2048 + tid * 8]);
            aptr0 += 32; aptr1 += 32; bptr0 += 32; bptr1 += 32;
        }
        // wait for tile t's 4 loads only; up to 8 newer loads stay in flight
        const int ahead = nk - 1 - t;
        if (ahead >= 2)      asm volatile("s_waitcnt vmcnt(8)" ::: "memory");
        else if (ahead == 1) asm volatile("s_waitcnt vmcnt(4)" ::: "memory");
        else                 asm volatile("s_waitcnt vmcnt(0)" ::: "memory");
        __builtin_amdgcn_s_barrier();   // all waves' share of tile t landed
        asm volatile("" ::: "memory");

        const _Float16* Asc = As[cb];
        const _Float16* Bsc = Bs[cb];
        half8 af[4], bf[4];
#pragma unroll
        for (int i = 0; i < 4; ++i) af[i] = *(const half8*)&Asc[((wm + i) * 64 + lane) * 8];
#pragma unroll
        for (int i = 0; i < 4; ++i) bf[i] = *(const half8*)&Bsc[((wn + i) * 64 + lane) * 8];
#pragma unroll
        for (int i = 0; i < 4; ++i)
#pragma unroll
            for (int j = 0; j < 4; ++j)
                acc[i][j] = __builtin_amdgcn_mfma_f32_16x16x32_f16(
                    af[i], bf[j], acc[i][j], 0, 0, 0);

        asm volatile("" ::: "memory");
        __builtin_amdgcn_s_barrier();   // readers of buf cb done before reuse
        cb = (cb == 2) ? 0 : cb + 1;
        wb = (wb == 2) ? 0 : wb + 1;
    }

    // Epilogue. C/D layout: col = lane&15, row = (lane>>4)*4 + reg.
    if (EPI == EPI_QKV) {
        const int part = col0 / 768;   // 0=q, 1=k, 2=v (tile never spans parts)
#pragma unroll
        for (int i = 0; i < 4; ++i) {
            int rowb = row0 + ((wm + i) << 4) + ((lane >> 4) << 2);
            int bidx = rowb >> 9;
            int s0   = rowb & 511;
#pragma unroll
            for (int j = 0; j < 4; ++j) {
                int col = col0 + ((wn + j) << 4) + (lane & 15);
                float bsv = bias[col];
                int hh = (col >> 6) % 12;
                int dd = col & 63;
                size_t hb = ((size_t)(bidx * 12 + hh)) << 15;  // *512*64
                if (part == 0) {
#pragma unroll
                    for (int r = 0; r < 4; ++r)
                        h16o[hb + (size_t)(s0 + r) * 64 + dd] =
                            (_Float16)((acc[i][j][r] + bsv) * 0.125f);
                } else if (part == 1) {
#pragma unroll
                    for (int r = 0; r < 4; ++r)
                        k16o[hb + (size_t)(s0 + r) * 64 + dd] =
                            (_Float16)(acc[i][j][r] + bsv);
                } else {
                    half4 pk;
#pragma unroll
                    for (int r = 0; r < 4; ++r)
                        pk[r] = (_Float16)(acc[i][j][r] + bsv);
                    *(half4*)&vTo[hb + (size_t)dd * 512 + s0] = pk;
                }
            }
        }
    } else {
#pragma unroll
        for (int i = 0; i < 4; ++i) {
            int rowb = row0 + ((wm + i) << 4) + ((lane >> 4) << 2);
#pragma unroll
            for (int j = 0; j < 4; ++j) {
                int col = col0 + ((wn + j) << 4) + (lane & 15);
                float bsv = bias[col];
#pragma unroll
                for (int r = 0; r < 4; ++r) {
                    int row = rowb + r;
                    float v = acc[i][j][r] + bsv;
                    if (EPI == EPI_BIAS_RES) {
                        v += resid[(size_t)row * N + col];
                        C[(size_t)row * N + col] = v;
                    }
                    if (EPI == EPI_BIAS_GELU) {
                        float u = v;
                        v = 0.5f * u * (1.0f + tanhf(0.7978845608028654f * (u + 0.044715f * u * u * u)));
                        h16o[(size_t)row * N + col] = (_Float16)v;
                    }
                }
            }
        }
    }
}

// ---------------------------------------------------------------------------
// MFMA flash attention. Block = (q-tile 64, head, batch); 4 waves x 16 q-rows.
// q16 pre-scaled by 1/8. k16: [b,h,s,d]. vT16: [b,h,d,s]. Out fp16 attnb16.
// LDS strides padded (72 f16 / 68 f32) -> all b128 patterns conflict-free.
// ---------------------------------------------------------------------------
__global__ __launch_bounds__(256) void attn_kernel(
    const _Float16* __restrict__ q16, const _Float16* __restrict__ k16,
    const _Float16* __restrict__ vT16, _Float16* __restrict__ attnb)
{
    const int qt = 7 - blockIdx.x;   // biggest q-tiles first
    const int h  = blockIdx.y;
    const int b  = blockIdx.z;
    const int tid  = threadIdx.x;
    const int lane = tid & 63;
    const int wave = tid >> 6;
    const int quad = lane >> 4;
    const int l15  = lane & 15;
    const int wq   = wave << 4;      // wave's q-row base in tile

    __shared__ _Float16 Kt[64 * 72];
    __shared__ _Float16 Vt[64 * 72];   // [d][key]
    __shared__ _Float16 Ps[64 * 72];
    __shared__ float    Ss[64 * 68];
    __shared__ float mS[64], lS[64], aS[64];

    const size_t headbase = ((size_t)(b * HH + h)) << 15;   // *512*64
    const int q0 = qt * 64;

    // Q fragments in registers for the whole kernel (A-operand layout)
    half8 qf0, qf1;
    {
        const _Float16* qp = q16 + headbase + (size_t)(q0 + wq + l15) * 64 + quad * 8;
        qf0 = *(const half8*)qp;
        qf1 = *(const half8*)(qp + 32);
    }
    if (tid < 64) { mS[tid] = -1e30f; lS[tid] = 0.f; }

    floatx4 o[4] = {};

    for (int kt = 0; kt <= qt; ++kt) {
        // --- stage K tile [key][d] and V^T tile [d][key] ---
        {
            int r = tid >> 2;
            int c = (tid & 3) << 4;
            const _Float16* kp = k16 + headbase + (size_t)(kt * 64 + r) * 64 + c;
            half8 k0 = *(const half8*)kp;
            half8 k1 = *(const half8*)(kp + 8);
            const _Float16* vp = vT16 + headbase + (size_t)r * 512 + kt * 64 + c;
            half8 v0 = *(const half8*)vp;
            half8 v1 = *(const half8*)(vp + 8);
            __syncthreads();   // previous iteration fully consumed LDS
            *(half8*)&Kt[r * 72 + c]     = k0;
            *(half8*)&Kt[r * 72 + c + 8] = k1;
            *(half8*)&Vt[r * 72 + c]     = v0;
            *(half8*)&Vt[r * 72 + c + 8] = v1;
        }
        __syncthreads();

        // --- S = Q K^T : 4 key-subtiles x 2 MFMA ---
        floatx4 s4[4];
#pragma unroll
        for (int t4 = 0; t4 < 4; ++t4) {
            half8 kf0 = *(const half8*)&Kt[(t4 * 16 + l15) * 72 + quad * 8];
            half8 kf1 = *(const half8*)&Kt[(t4 * 16 + l15) * 72 + quad * 8 + 32];
            floatx4 a = {};
            a = __builtin_amdgcn_mfma_f32_16x16x32_f16(qf0, kf0, a, 0, 0, 0);
            a = __builtin_amdgcn_mfma_f32_16x16x32_f16(qf1, kf1, a, 0, 0, 0);
            s4[t4] = a;
        }

        // --- causal mask on diagonal tile ---
        if (kt == qt) {
#pragma unroll
            for (int t4 = 0; t4 < 4; ++t4) {
                int kc = t4 * 16 + l15;
#pragma unroll
                for (int r = 0; r < 4; ++r)
                    if (kc > wq + quad * 4 + r) s4[t4][r] = -1e30f;
            }
        }

        // --- scores to LDS (C-layout scatter, conflict-free) ---
#pragma unroll
        for (int t4 = 0; t4 < 4; ++t4)
#pragma unroll
            for (int r = 0; r < 4; ++r)
                Ss[(wq + quad * 4 + r) * 68 + t4 * 16 + l15] = s4[t4][r];
        __syncthreads();

        // --- online softmax: 4 lanes per row, 16 cols each ---
        {
            int rr = tid >> 2, sub = tid & 3;
            float4 p0 = *(const float4*)&Ss[rr * 68 + sub * 16 + 0];
            float4 p1 = *(const float4*)&Ss[rr * 68 + sub * 16 + 4];
            float4 p2 = *(const float4*)&Ss[rr * 68 + sub * 16 + 8];
            float4 p3 = *(const float4*)&Ss[rr * 68 + sub * 16 + 12];
            float tmax = fmaxf(fmaxf(fmaxf(p0.x, p0.y), fmaxf(p0.z, p0.w)),
                         fmaxf(fmaxf(fmaxf(p1.x, p1.y), fmaxf(p1.z, p1.w)),
                         fmaxf(fmaxf(fmaxf(p2.x, p2.y), fmaxf(p2.z, p2.w)),
                               fmaxf(fmaxf(p3.x, p3.y), fmaxf(p3.z, p3.w)))));
            tmax = fmaxf(tmax, __shfl_xor(tmax, 1));
            tmax = fmaxf(tmax, __shfl_xor(tmax, 2));
            float mold = mS[rr];
            float mnew = fmaxf(mold, tmax);
            p0.x = __expf(p0.x - mnew); p0.y = __expf(p0.y - mnew);
            p0.z = __expf(p0.z - mnew); p0.w = __expf(p0.w - mnew);
            p1.x = __expf(p1.x - mnew); p1.y = __expf(p1.y - mnew);
            p1.z = __expf(p1.z - mnew); p1.w = __expf(p1.w - mnew);
            p2.x = __expf(p2.x - mnew); p2.y = __expf(p2.y - mnew);
            p2.z = __expf(p2.z - mnew); p2.w = __expf(p2.w - mnew);
            p3.x = __expf(p3.x - mnew); p3.y = __expf(p3.y - mnew);
            p3.z = __expf(p3.z - mnew); p3.w = __expf(p3.w - mnew);
            float sum = p0.x + p0.y + p0.z + p0.w + p1.x + p1.y + p1.z + p1.w
                      + p2.x + p2.y + p2.z + p2.w + p3.x + p3.y + p3.z + p3.w;
            sum += __shfl_xor(sum, 1);
            sum += __shfl_xor(sum, 2);
            half8 ph0, ph1;
            ph0[0] = (_Float16)p0.x; ph0[1] = (_Float16)p0.y;
            ph0[2] = (_Float16)p0.z; ph0[3] = (_Float16)p0.w;
            ph0[4] = (_Float16)p1.x; ph0[5] = (_Float16)p1.y;
            ph0[6] = (_Float16)p1.z; ph0[7] = (_Float16)p1.w;
            ph1[0] = (_Float16)p2.x; ph1[1] = (_Float16)p2.y;
            ph1[2] = (_Float16)p2.z; ph1[3] = (_Float16)p2.w;
            ph1[4] = (_Float16)p3.x; ph1[5] = (_Float16)p3.y;
            ph1[6] = (_Float16)p3.z; ph1[7] = (_Float16)p3.w;
            *(half8*)&Ps[rr * 72 + sub * 16]     = ph0;
            *(half8*)&Ps[rr * 72 + sub * 16 + 8] = ph1;
            if (sub == 0) {
                float al = __expf(mold - mnew);
                aS[rr] = al;
                mS[rr] = mnew;
                lS[rr] = lS[rr] * al + sum;
            }
        }
        __syncthreads();

        // --- O = O*alpha + P @ V ---
        {
            float al[4];
#pragma unroll
            for (int r = 0; r < 4; ++r) al[r] = aS[wq + quad * 4 + r];
#pragma unroll
            for (int dt = 0; dt < 4; ++dt)
#pragma unroll
                for (int r = 0; r < 4; ++r) o[dt][r] *= al[r];

            half8 pf0 = *(const half8*)&Ps[(wq + l15) * 72 + quad * 8];
            half8 pf1 = *(const half8*)&Ps[(wq + l15) * 72 + quad * 8 + 32];
#pragma unroll
            for (int dt = 0; dt < 4; ++dt) {
                half8 vf0 = *(const half8*)&Vt[(dt * 16 + l15) * 72 + quad * 8];
                half8 vf1 = *(const half8*)&Vt[(dt * 16 + l15) * 72 + quad * 8 + 32];
                o[dt] = __builtin_amdgcn_mfma_f32_16x16x32_f16(pf0, vf0, o[dt], 0, 0, 0);
                o[dt] = __builtin_amdgcn_mfma_f32_16x16x32_f16(pf1, vf1, o[dt], 0, 0, 0);
            }
        }
    }

    // --- finalize: O / l, write fp16 [token][768] ---
    float inv[4];
#pragma unroll
    for (int r = 0; r < 4; ++r) inv[r] = 1.0f / lS[wq + quad * 4 + r];
#pragma unroll
    for (int dt = 0; dt < 4; ++dt) {
        int col = h * 64 + dt * 16 + l15;
#pragma unroll
        for (int r = 0; r < 4; ++r) {
            int row = b * SS + q0 + wq + quad * 4 + r;
            attnb[(size_t)row * DD + col] = (_Float16)(o[dt][r] * inv[r]);
        }
    }
}

// ---------------------------------------------------------------------------
// LayerNorm over last dim (768). One block per row; in-place safe.
// Optional fp16 mirror output for next GEMM's A operand.
// ---------------------------------------------------------------------------
__global__ __launch_bounds__(256) void ln_kernel(
    const float* __restrict__ in, const float* __restrict__ gam,
    const float* __restrict__ bet, float* __restrict__ out,
    _Float16* __restrict__ out16)
{
    int row = blockIdx.x;
    int tid = threadIdx.x;
    const float* p = in + (size_t)row * DD;
    float v0 = p[tid], v1 = p[tid + 256], v2 = p[tid + 512];

    __shared__ float red[256];
    red[tid] = v0 + v1 + v2;
    __syncthreads();
    for (int off = 128; off > 0; off >>= 1) {
        if (tid < off) red[tid] += red[tid + off];
        __syncthreads();
    }
    float mean = red[0] * (1.0f / DD);
    __syncthreads();

    float d0 = v0 - mean, d1 = v1 - mean, d2 = v2 - mean;
    red[tid] = d0 * d0 + d1 * d1 + d2 * d2;
    __syncthreads();
    for (int off = 128; off > 0; off >>= 1) {
        if (tid < off) red[tid] += red[tid + off];
        __syncthreads();
    }
    float rstd = rsqrtf(red[0] * (1.0f / DD) + 1e-5f);

    float* o = out + (size_t)row * DD;
    float r0 = gam[tid]       * (d0 * rstd) + bet[tid];
    float r1 = gam[tid + 256] * (d1 * rstd) + bet[tid + 256];
    float r2 = gam[tid + 512] * (d2 * rstd) + bet[tid + 512];
    o[tid] = r0; o[tid + 256] = r1; o[tid + 512] = r2;
    if (out16) {
        _Float16* oh = out16 + (size_t)row * DD;
        oh[tid] = (_Float16)r0; oh[tid + 256] = (_Float16)r1; oh[tid + 512] = (_Float16)r2;
    }
}

// ---------------------------------------------------------------------------
extern "C" void kernel_launch(void* const* d_in, const int* in_sizes, int n_in,
                              void* d_out, int out_size, void* d_ws, size_t ws_size,
                              hipStream_t stream)
{
    const int*   tokens = (const int*)d_in[0];
    const float* we     = (const float*)d_in[1];
    const float* wqkv   = (const float*)d_in[2];
    const float* bqkv   = (const float*)d_in[3];
    const float* wproj  = (const float*)d_in[4];
    const float* bproj  = (const float*)d_in[5];
    const float* g1     = (const float*)d_in[6];
    const float* b1     = (const float*)d_in[7];
    const float* wfc    = (const float*)d_in[8];
    const float* bfc    = (const float*)d_in[9];
    const float* wpr    = (const float*)d_in[10];
    const float* bpr    = (const float*)d_in[11];
    const float* g2     = (const float*)d_in[12];
    const float* b2     = (const float*)d_in[13];
    float* out = (float*)d_out;

    // Workspace (72.4 MB):
    //   x f32 (12.6M) | n f32 (12.6M) | x16 (6.3M) | n16 (6.3M) |
    //   WBUF fp16 weights (9.44M: qkv_t 1.77M | proj_t 0.59M | fc_t 2.36M;
    //     wpr_t 2.36M halves reuses WBUF base after FC1) |
    //   BIG (25.2M union): q16,k16,vT16 (18.9M) + attnb16 (6.3M tail) ;
    //                      t f32 (12.6M head, after q/k dead) ; m16 (whole)
    float* x   = (float*)d_ws;
    float* n   = x + (size_t)MM * DD;
    _Float16* x16  = (_Float16*)(n + (size_t)MM * DD);
    _Float16* n16  = x16 + (size_t)MM * DD;
    _Float16* WBUF = n16 + (size_t)MM * DD;
    _Float16* wq_t = WBUF;                               // 2304x768
    _Float16* wp_t = wq_t + (size_t)2304 * DD;           // 768x768
    _Float16* wf_t = wp_t + (size_t)DD * DD;             // 3072x768
    _Float16* wr_t = WBUF;                               // 768x3072 (reuse)
    _Float16* BIG  = wf_t + (size_t)DFF * DD;
    _Float16* q16  = BIG;
    _Float16* k16  = q16 + (size_t)MM * DD;
    _Float16* vT16 = k16 + (size_t)MM * DD;
    _Float16* attnb16 = vT16 + (size_t)MM * DD;
    float*    t   = (float*)BIG;
    _Float16* m16 = BIG;

    embed_kernel<<<dim3(MM), 256, 0, stream>>>(tokens, we, x, x16);

    for (int l = 0; l < LL; ++l) {
        // Convert wqkv + wproj + wfc (one dispatch, 1152 tiles)
        convw3_kernel<<<dim3(1152), 256, 0, stream>>>(
            wqkv + (size_t)l * DD * 2304, wproj + (size_t)l * DD * DD,
            wfc + (size_t)l * DD * DFF, wq_t, wp_t, wf_t);
        // QKV projection -> fp16 q/k/vT buffers
        gemm_h_kernel<EPI_QKV><<<dim3(2304 / 128, MM / 128), 256, 0, stream>>>(
            x16, wq_t, bqkv + (size_t)l * 2304, nullptr, nullptr,
            q16, k16, vT16, MM, 2304, DD);
        // MFMA flash attention -> fp16 attnb
        attn_kernel<<<dim3(SS / 64, HH, BB), 256, 0, stream>>>(q16, k16, vT16, attnb16);
        // Output projection + residual(x) -> t fp32
        gemm_h_kernel<EPI_BIAS_RES><<<dim3(DD / 128, MM / 128), 256, 0, stream>>>(
            attnb16, wp_t, bproj + (size_t)l * DD,
            x, t, nullptr, nullptr, nullptr, MM, DD, DD);
        // LN1 -> n fp32 + n16
        ln_kernel<<<dim3(MM), 256, 0, stream>>>(t, g1 + (size_t)l * DD,
                                                b1 + (size_t)l * DD, n, n16);
        // FC + GELU -> m16 fp16
        gemm_h_kernel<EPI_BIAS_GELU><<<dim3(DFF / 128, MM / 128), 256, 0, stream>>>(
            n16, wf_t, bfc + (size_t)l * DFF, nullptr, nullptr,
            m16, nullptr, nullptr, MM, DFF, DD);
        // Convert wpr (reuses WBUF base; qkv/proj/fc weights dead now)
        convw_kernel<<<dim3(576), 256, 0, stream>>>(
            wpr + (size_t)l * DFF * DD, wr_t, DFF, DD);
        // FC2 + residual(n) -> x fp32
        gemm_h_kernel<EPI_BIAS_RES><<<dim3(DD / 128, MM / 128), 256, 0, stream>>>(
            m16, wr_t, bpr + (size_t)l * DD,
            n, x, nullptr, nullptr, nullptr, MM, DD, DFF);
        // LN2 (in-place on x; last layer writes d_out, no fp16 mirror needed)
        ln_kernel<<<dim3(MM), 256, 0, stream>>>(x, g2 + (size_t)l * DD,
                                                b2 + (size_t)l * DD,
                                                (l == LL - 1) ? out : x,
                                                (l == LL - 1) ? nullptr : x16);
    }
}

// Round 4
// 3250.493 us; speedup vs baseline: 1.0921x; 1.0142x over previous
//
#include <hip/hip_runtime.h>
#include <math.h>

// Problem constants
#define BB 8
#define SS 512
#define DD 768
#define HH 12
#define LL 12
#define DFF 3072
#define VV 40478
#define MM (BB*SS)   // 4096 rows

typedef _Float16 half8 __attribute__((ext_vector_type(8)));
typedef _Float16 half4 __attribute__((ext_vector_type(4)));
typedef float floatx4 __attribute__((ext_vector_type(4)));

// async global->LDS, 16B per lane, LDS dest = wave-uniform base + lane*16
#define GLDS(gptr, lptr) \
    __builtin_amdgcn_global_load_lds( \
        (const __attribute__((address_space(1))) void*)(gptr), \
        (__attribute__((address_space(3))) void*)(lptr), 16, 0, 0)

// ---------------------------------------------------------------------------
// Embedding: x[b,s,:] = we[tok[b,s],:] + we[V+s,:]  (fp32 + fp16 mirror)
// ---------------------------------------------------------------------------
__global__ __launch_bounds__(256) void embed_kernel(
    const int* __restrict__ tokens, const float* __restrict__ we,
    float* __restrict__ x, _Float16* __restrict__ x16)
{
    int i = blockIdx.x;
    int s = i & (SS - 1);
    int tok = tokens[i];
    const float* wt = we + (size_t)tok * DD;
    const float* wp = we + (size_t)(VV + s) * DD;
    float* xr = x + (size_t)i * DD;
    _Float16* hr = x16 + (size_t)i * DD;
    for (int d = threadIdx.x; d < DD; d += 256) {
        float v = wt[d] + wp[d];
        xr[d] = v;
        hr[d] = (_Float16)v;
    }
}

// ---------------------------------------------------------------------------
// Weight convert: W fp32 [K][N] -> Wt fp16 [N][K] (transpose), 64x64 tiles.
// convw3_kernel: wqkv + wproj + wfc of one layer in a single dispatch.
// convw_kernel: single matrix (used for wpr, overlapping WBUF reuse).
// ---------------------------------------------------------------------------
__device__ __forceinline__ void convw_tile(
    const float* __restrict__ W, _Float16* __restrict__ Wt,
    int K, int N, int n0, int k0)
{
    __shared__ float tile[64][65];
    const int t = threadIdx.x;
    const int c  = t & 63;
    const int r4 = t >> 6;           // 0..3
#pragma unroll
    for (int rr = 0; rr < 64; rr += 4)
        tile[rr + r4][c] = W[(size_t)(k0 + rr + r4) * N + n0 + c];
    __syncthreads();
#pragma unroll
    for (int nn = 0; nn < 64; nn += 4) {
        int n = nn + r4;
        Wt[(size_t)(n0 + n) * K + k0 + c] = (_Float16)tile[c][n];
    }
}

__global__ __launch_bounds__(256) void convw_kernel(
    const float* __restrict__ W, _Float16* __restrict__ Wt, int K, int N)
{
    const int ntx = N >> 6;
    const int b = blockIdx.x;
    convw_tile(W, Wt, K, N, (b % ntx) * 64, (b / ntx) * 64);
}

__global__ __launch_bounds__(256) void convw3_kernel(
    const float* __restrict__ w0, const float* __restrict__ w1,
    const float* __restrict__ w2,
    _Float16* __restrict__ o0, _Float16* __restrict__ o1,
    _Float16* __restrict__ o2)
{
    int b = blockIdx.x;
    const float* W; _Float16* Wt; int N, tb;
    if (b < 432)       { W = w0; Wt = o0; N = 2304; tb = b; }
    else if (b < 576)  { W = w1; Wt = o1; N = 768;  tb = b - 432; }
    else               { W = w2; Wt = o2; N = 3072; tb = b - 576; }
    const int ntx = N >> 6;
    convw_tile(W, Wt, 768, N, (tb % ntx) * 64, (tb / ntx) * 64);
}

// ---------------------------------------------------------------------------
// fp16-MFMA GEMM: A fp16 [M][K], Bt fp16 [N][K]. 128x128 tile, BK=32,
// 256 threads (4 waves, 64x64 each). Both tiles staged with
// global_load_lds width=16 into fragment-order LDS (chunk = tid, linear).
// LDS dest base hoisted to SGPR via readfirstlane (wave-uniform; avoids
// the divergent-pointer waterfall). 3-stage pipeline: issue distance 2,
// steady-state vmcnt(8) (T3+T4 counted-vmcnt). XCD-aware block swizzle.
// Epilogues: BIAS_RES (fp32 C=acc+bias+resid), BIAS_GELU (fp16 out),
// QKV (fp16 q scaled, k, transposed vT).
// ---------------------------------------------------------------------------
#define EPI_BIAS_RES 1
#define EPI_BIAS_GELU 2
#define EPI_QKV 3

template<int EPI>
__global__ __launch_bounds__(256) void gemm_h_kernel(
    const _Float16* __restrict__ A, const _Float16* __restrict__ Bt,
    const float* __restrict__ bias, const float* __restrict__ resid,
    float* __restrict__ C, _Float16* __restrict__ h16o,
    _Float16* __restrict__ k16o, _Float16* __restrict__ vTo,
    int M, int N, int K)
{
    __shared__ _Float16 As[3][4096];   // 128 rows x 32 k, chunk order
    __shared__ _Float16 Bs[3][4096];   // 128 cols x 32 k, chunk order

    const int tid  = threadIdx.x;
    const int lane = tid & 63;
    const int wave = tid >> 6;

    // wave-uniform LDS base (halves): wave*512; lane l lands at +l*16B,
    // i.e. half-index (wave*64+l)*8 == tid*8 -- same layout as before.
    const int wbase = __builtin_amdgcn_readfirstlane(wave << 9);

    // XCD-aware bijective swizzle (all grids are multiples of 8 blocks):
    // consecutive logical tiles land on the same XCD -> A-panel L2 reuse.
    const int gx  = gridDim.x;
    const int lb  = blockIdx.y * gx + blockIdx.x;
    const int q8  = (gx * gridDim.y) >> 3;
    const int swz = (lb & 7) * q8 + (lb >> 3);
    const int row0 = (swz / gx) * 128, col0 = (swz % gx) * 128;

    // staging: thread's (row, kchunk) chosen so LDS chunk index == tid
    const int srow = ((tid >> 6) << 4) + (tid & 15);   // 0..63
    const int skc  = (tid >> 4) & 3;                   // kchunk 0..3
    const _Float16* aptr0 = A  + (size_t)(row0 + srow) * K      + skc * 8;
    const _Float16* aptr1 = A  + (size_t)(row0 + 64 + srow) * K + skc * 8;
    const _Float16* bptr0 = Bt + (size_t)(col0 + srow) * K      + skc * 8;
    const _Float16* bptr1 = Bt + (size_t)(col0 + 64 + srow) * K + skc * 8;

    const int wm = (wave >> 1) << 2;
    const int wn = (wave & 1) << 2;

    floatx4 acc[4][4] = {};

    const int nk = K >> 5;

    // prologue: stage tiles 0 and 1 into buffers 0 and 1
    GLDS(aptr0, &As[0][wbase]);
    GLDS(aptr1, &As[0][2048 + wbase]);
    GLDS(bptr0, &Bs[0][wbase]);
    GLDS(bptr1, &Bs[0][2048 + wbase]);
    aptr0 += 32; aptr1 += 32; bptr0 += 32; bptr1 += 32;
    GLDS(aptr0, &As[1][wbase]);
    GLDS(aptr1, &As[1][2048 + wbase]);
    GLDS(bptr0, &Bs[1][wbase]);
    GLDS(bptr1, &Bs[1][2048 + wbase]);
    aptr0 += 32; aptr1 += 32; bptr0 += 32; bptr1 += 32;

    int cb = 0;   // compute buffer
    int wb = 2;   // write (stage) buffer

    for (int t = 0; t < nk; ++t) {
        if (t + 2 < nk) {
            // buffer wb's previous contents were consumed at iter t-1;
            // the trailing barrier of iter t-1 makes this overwrite safe.
            GLDS(aptr0, &As[wb][wbase]);
            GLDS(aptr1, &As[wb][2048 + wbase]);
            GLDS(bptr0, &Bs[wb][wbase]);
            GLDS(bptr1, &Bs[wb][2048 + wbase]);
            aptr0 += 32; aptr1 += 32; bptr0 += 32; bptr1 += 32;
        }
        // wait for tile t's 4 loads only; up to 8 newer loads stay in flight
        const int ahead = nk - 1 - t;
        if (ahead >= 2)      asm volatile("s_waitcnt vmcnt(8)" ::: "memory");
        else if (ahead == 1) asm volatile("s_waitcnt vmcnt(4)" ::: "memory");
        else                 asm volatile("s_waitcnt vmcnt(0)" ::: "memory");
        __builtin_amdgcn_s_barrier();   // all waves' share of tile t landed
        asm volatile("" ::: "memory");

        const _Float16* Asc = As[cb];
        const _Float16* Bsc = Bs[cb];
        half8 af[4], bf[4];
#pragma unroll
        for (int i = 0; i < 4; ++i) af[i] = *(const half8*)&Asc[((wm + i) * 64 + lane) * 8];
#pragma unroll
        for (int i = 0; i < 4; ++i) bf[i] = *(const half8*)&Bsc[((wn + i) * 64 + lane) * 8];
#pragma unroll
        for (int i = 0; i < 4; ++i)
#pragma unroll
            for (int j = 0; j < 4; ++j)
                acc[i][j] = __builtin_amdgcn_mfma_f32_16x16x32_f16(
                    af[i], bf[j], acc[i][j], 0, 0, 0);

        asm volatile("" ::: "memory");
        __builtin_amdgcn_s_barrier();   // readers of buf cb done before reuse
        cb = (cb == 2) ? 0 : cb + 1;
        wb = (wb == 2) ? 0 : wb + 1;
    }

    // Epilogue. C/D layout: col = lane&15, row = (lane>>4)*4 + reg.
    if (EPI == EPI_QKV) {
        const int part = col0 / 768;   // 0=q, 1=k, 2=v (tile never spans parts)
#pragma unroll
        for (int i = 0; i < 4; ++i) {
            int rowb = row0 + ((wm + i) << 4) + ((lane >> 4) << 2);
            int bidx = rowb >> 9;
            int s0   = rowb & 511;
#pragma unroll
            for (int j = 0; j < 4; ++j) {
                int col = col0 + ((wn + j) << 4) + (lane & 15);
                float bsv = bias[col];
                int hh = (col >> 6) % 12;
                int dd = col & 63;
                size_t hb = ((size_t)(bidx * 12 + hh)) << 15;  // *512*64
                if (part == 0) {
#pragma unroll
                    for (int r = 0; r < 4; ++r)
                        h16o[hb + (size_t)(s0 + r) * 64 + dd] =
                            (_Float16)((acc[i][j][r] + bsv) * 0.125f);
                } else if (part == 1) {
#pragma unroll
                    for (int r = 0; r < 4; ++r)
                        k16o[hb + (size_t)(s0 + r) * 64 + dd] =
                            (_Float16)(acc[i][j][r] + bsv);
                } else {
                    half4 pk;
#pragma unroll
                    for (int r = 0; r < 4; ++r)
                        pk[r] = (_Float16)(acc[i][j][r] + bsv);
                    *(half4*)&vTo[hb + (size_t)dd * 512 + s0] = pk;
                }
            }
        }
    } else {
#pragma unroll
        for (int i = 0; i < 4; ++i) {
            int rowb = row0 + ((wm + i) << 4) + ((lane >> 4) << 2);
#pragma unroll
            for (int j = 0; j < 4; ++j) {
                int col = col0 + ((wn + j) << 4) + (lane & 15);
                float bsv = bias[col];
#pragma unroll
                for (int r = 0; r < 4; ++r) {
                    int row = rowb + r;
                    float v = acc[i][j][r] + bsv;
                    if (EPI == EPI_BIAS_RES) {
                        v += resid[(size_t)row * N + col];
                        C[(size_t)row * N + col] = v;
                    }
                    if (EPI == EPI_BIAS_GELU) {
                        float u = v;
                        v = 0.5f * u * (1.0f + tanhf(0.7978845608028654f * (u + 0.044715f * u * u * u)));
                        h16o[(size_t)row * N + col] = (_Float16)v;
                    }
                }
            }
        }
    }
}

// ---------------------------------------------------------------------------
// MFMA flash attention. Block = (q-tile 64, head, batch); 4 waves x 16 q-rows.
// q16 pre-scaled by 1/8. k16: [b,h,s,d]. vT16: [b,h,d,s]. Out fp16 attnb16.
// LDS strides padded (72 f16 / 68 f32) -> all b128 patterns conflict-free.
// ---------------------------------------------------------------------------
__global__ __launch_bounds__(256) void attn_kernel(
    const _Float16* __restrict__ q16, const _Float16* __restrict__ k16,
    const _Float16* __restrict__ vT16, _Float16* __restrict__ attnb)
{
    const int qt = 7 - blockIdx.x;   // biggest q-tiles first
    const int h  = blockIdx.y;
    const int b  = blockIdx.z;
    const int tid  = threadIdx.x;
    const int lane = tid & 63;
    const int wave = tid >> 6;
    const int quad = lane >> 4;
    const int l15  = lane & 15;
    const int wq   = wave << 4;      // wave's q-row base in tile

    __shared__ _Float16 Kt[64 * 72];
    __shared__ _Float16 Vt[64 * 72];   // [d][key]
    __shared__ _Float16 Ps[64 * 72];
    __shared__ float    Ss[64 * 68];
    __shared__ float mS[64], lS[64], aS[64];

    const size_t headbase = ((size_t)(b * HH + h)) << 15;   // *512*64
    const int q0 = qt * 64;

    // Q fragments in registers for the whole kernel (A-operand layout)
    half8 qf0, qf1;
    {
        const _Float16* qp = q16 + headbase + (size_t)(q0 + wq + l15) * 64 + quad * 8;
        qf0 = *(const half8*)qp;
        qf1 = *(const half8*)(qp + 32);
    }
    if (tid < 64) { mS[tid] = -1e30f; lS[tid] = 0.f; }

    floatx4 o[4] = {};

    for (int kt = 0; kt <= qt; ++kt) {
        // --- stage K tile [key][d] and V^T tile [d][key] ---
        {
            int r = tid >> 2;
            int c = (tid & 3) << 4;
            const _Float16* kp = k16 + headbase + (size_t)(kt * 64 + r) * 64 + c;
            half8 k0 = *(const half8*)kp;
            half8 k1 = *(const half8*)(kp + 8);
            const _Float16* vp = vT16 + headbase + (size_t)r * 512 + kt * 64 + c;
            half8 v0 = *(const half8*)vp;
            half8 v1 = *(const half8*)(vp + 8);
            __syncthreads();   // previous iteration fully consumed LDS
            *(half8*)&Kt[r * 72 + c]     = k0;
            *(half8*)&Kt[r * 72 + c + 8] = k1;
            *(half8*)&Vt[r * 72 + c]     = v0;
            *(half8*)&Vt[r * 72 + c + 8] = v1;
        }
        __syncthreads();

        // --- S = Q K^T : 4 key-subtiles x 2 MFMA ---
        floatx4 s4[4];
#pragma unroll
        for (int t4 = 0; t4 < 4; ++t4) {
            half8 kf0 = *(const half8*)&Kt[(t4 * 16 + l15) * 72 + quad * 8];
            half8 kf1 = *(const half8*)&Kt[(t4 * 16 + l15) * 72 + quad * 8 + 32];
            floatx4 a = {};
            a = __builtin_amdgcn_mfma_f32_16x16x32_f16(qf0, kf0, a, 0, 0, 0);
            a = __builtin_amdgcn_mfma_f32_16x16x32_f16(qf1, kf1, a, 0, 0, 0);
            s4[t4] = a;
        }

        // --- causal mask on diagonal tile ---
        if (kt == qt) {
#pragma unroll
            for (int t4 = 0; t4 < 4; ++t4) {
                int kc = t4 * 16 + l15;
#pragma unroll
                for (int r = 0; r < 4; ++r)
                    if (kc > wq + quad * 4 + r) s4[t4][r] = -1e30f;
            }
        }

        // --- scores to LDS (C-layout scatter, conflict-free) ---
#pragma unroll
        for (int t4 = 0; t4 < 4; ++t4)
#pragma unroll
            for (int r = 0; r < 4; ++r)
                Ss[(wq + quad * 4 + r) * 68 + t4 * 16 + l15] = s4[t4][r];
        __syncthreads();

        // --- online softmax: 4 lanes per row, 16 cols each ---
        {
            int rr = tid >> 2, sub = tid & 3;
            float4 p0 = *(const float4*)&Ss[rr * 68 + sub * 16 + 0];
            float4 p1 = *(const float4*)&Ss[rr * 68 + sub * 16 + 4];
            float4 p2 = *(const float4*)&Ss[rr * 68 + sub * 16 + 8];
            float4 p3 = *(const float4*)&Ss[rr * 68 + sub * 16 + 12];
            float tmax = fmaxf(fmaxf(fmaxf(p0.x, p0.y), fmaxf(p0.z, p0.w)),
                         fmaxf(fmaxf(fmaxf(p1.x, p1.y), fmaxf(p1.z, p1.w)),
                         fmaxf(fmaxf(fmaxf(p2.x, p2.y), fmaxf(p2.z, p2.w)),
                               fmaxf(fmaxf(p3.x, p3.y), fmaxf(p3.z, p3.w)))));
            tmax = fmaxf(tmax, __shfl_xor(tmax, 1));
            tmax = fmaxf(tmax, __shfl_xor(tmax, 2));
            float mold = mS[rr];
            float mnew = fmaxf(mold, tmax);
            p0.x = __expf(p0.x - mnew); p0.y = __expf(p0.y - mnew);
            p0.z = __expf(p0.z - mnew); p0.w = __expf(p0.w - mnew);
            p1.x = __expf(p1.x - mnew); p1.y = __expf(p1.y - mnew);
            p1.z = __expf(p1.z - mnew); p1.w = __expf(p1.w - mnew);
            p2.x = __expf(p2.x - mnew); p2.y = __expf(p2.y - mnew);
            p2.z = __expf(p2.z - mnew); p2.w = __expf(p2.w - mnew);
            p3.x = __expf(p3.x - mnew); p3.y = __expf(p3.y - mnew);
            p3.z = __expf(p3.z - mnew); p3.w = __expf(p3.w - mnew);
            float sum = p0.x + p0.y + p0.z + p0.w + p1.x + p1.y + p1.z + p1.w
                      + p2.x + p2.y + p2.z + p2.w + p3.x + p3.y + p3.z + p3.w;
            sum += __shfl_xor(sum, 1);
            sum += __shfl_xor(sum, 2);
            half8 ph0, ph1;
            ph0[0] = (_Float16)p0.x; ph0[1] = (_Float16)p0.y;
            ph0[2] = (_Float16)p0.z; ph0[3] = (_Float16)p0.w;
            ph0[4] = (_Float16)p1.x; ph0[5] = (_Float16)p1.y;
            ph0[6] = (_Float16)p1.z; ph0[7] = (_Float16)p1.w;
            ph1[0] = (_Float16)p2.x; ph1[1] = (_Float16)p2.y;
            ph1[2] = (_Float16)p2.z; ph1[3] = (_Float16)p2.w;
            ph1[4] = (_Float16)p3.x; ph1[5] = (_Float16)p3.y;
            ph1[6] = (_Float16)p3.z; ph1[7] = (_Float16)p3.w;
            *(half8*)&Ps[rr * 72 + sub * 16]     = ph0;
            *(half8*)&Ps[rr * 72 + sub * 16 + 8] = ph1;
            if (sub == 0) {
                float al = __expf(mold - mnew);
                aS[rr] = al;
                mS[rr] = mnew;
                lS[rr] = lS[rr] * al + sum;
            }
        }
        __syncthreads();

        // --- O = O*alpha + P @ V ---
        {
            float al[4];
#pragma unroll
            for (int r = 0; r < 4; ++r) al[r] = aS[wq + quad * 4 + r];
#pragma unroll
            for (int dt = 0; dt < 4; ++dt)
#pragma unroll
                for (int r = 0; r < 4; ++r) o[dt][r] *= al[r];

            half8 pf0 = *(const half8*)&Ps[(wq + l15) * 72 + quad * 8];
            half8 pf1 = *(const half8*)&Ps[(wq + l15) * 72 + quad * 8 + 32];
#pragma unroll
            for (int dt = 0; dt < 4; ++dt) {
                half8 vf0 = *(const half8*)&Vt[(dt * 16 + l15) * 72 + quad * 8];
                half8 vf1 = *(const half8*)&Vt[(dt * 16 + l15) * 72 + quad * 8 + 32];
                o[dt] = __builtin_amdgcn_mfma_f32_16x16x32_f16(pf0, vf0, o[dt], 0, 0, 0);
                o[dt] = __builtin_amdgcn_mfma_f32_16x16x32_f16(pf1, vf1, o[dt], 0, 0, 0);
            }
        }
    }

    // --- finalize: O / l, write fp16 [token][768] ---
    float inv[4];
#pragma unroll
    for (int r = 0; r < 4; ++r) inv[r] = 1.0f / lS[wq + quad * 4 + r];
#pragma unroll
    for (int dt = 0; dt < 4; ++dt) {
        int col = h * 64 + dt * 16 + l15;
#pragma unroll
        for (int r = 0; r < 4; ++r) {
            int row = b * SS + q0 + wq + quad * 4 + r;
            attnb[(size_t)row * DD + col] = (_Float16)(o[dt][r] * inv[r]);
        }
    }
}

// ---------------------------------------------------------------------------
// LayerNorm over last dim (768). One block per row; in-place safe.
// Optional fp16 mirror output for next GEMM's A operand.
// ---------------------------------------------------------------------------
__global__ __launch_bounds__(256) void ln_kernel(
    const float* __restrict__ in, const float* __restrict__ gam,
    const float* __restrict__ bet, float* __restrict__ out,
    _Float16* __restrict__ out16)
{
    int row = blockIdx.x;
    int tid = threadIdx.x;
    const float* p = in + (size_t)row * DD;
    float v0 = p[tid], v1 = p[tid + 256], v2 = p[tid + 512];

    __shared__ float red[256];
    red[tid] = v0 + v1 + v2;
    __syncthreads();
    for (int off = 128; off > 0; off >>= 1) {
        if (tid < off) red[tid] += red[tid + off];
        __syncthreads();
    }
    float mean = red[0] * (1.0f / DD);
    __syncthreads();

    float d0 = v0 - mean, d1 = v1 - mean, d2 = v2 - mean;
    red[tid] = d0 * d0 + d1 * d1 + d2 * d2;
    __syncthreads();
    for (int off = 128; off > 0; off >>= 1) {
        if (tid < off) red[tid] += red[tid + off];
        __syncthreads();
    }
    float rstd = rsqrtf(red[0] * (1.0f / DD) + 1e-5f);

    float* o = out + (size_t)row * DD;
    float r0 = gam[tid]       * (d0 * rstd) + bet[tid];
    float r1 = gam[tid + 256] * (d1 * rstd) + bet[tid + 256];
    float r2 = gam[tid + 512] * (d2 * rstd) + bet[tid + 512];
    o[tid] = r0; o[tid + 256] = r1; o[tid + 512] = r2;
    if (out16) {
        _Float16* oh = out16 + (size_t)row * DD;
        oh[tid] = (_Float16)r0; oh[tid + 256] = (_Float16)r1; oh[tid + 512] = (_Float16)r2;
    }
}

// ---------------------------------------------------------------------------
extern "C" void kernel_launch(void* const* d_in, const int* in_sizes, int n_in,
                              void* d_out, int out_size, void* d_ws, size_t ws_size,
                              hipStream_t stream)
{
    const int*   tokens = (const int*)d_in[0];
    const float* we     = (const float*)d_in[1];
    const float* wqkv   = (const float*)d_in[2];
    const float* bqkv   = (const float*)d_in[3];
    const float* wproj  = (const float*)d_in[4];
    const float* bproj  = (const float*)d_in[5];
    const float* g1     = (const float*)d_in[6];
    const float* b1     = (const float*)d_in[7];
    const float* wfc    = (const float*)d_in[8];
    const float* bfc    = (const float*)d_in[9];
    const float* wpr    = (const float*)d_in[10];
    const float* bpr    = (const float*)d_in[11];
    const float* g2     = (const float*)d_in[12];
    const float* b2     = (const float*)d_in[13];
    float* out = (float*)d_out;

    // Workspace (72.4 MB):
    //   x f32 (12.6M) | n f32 (12.6M) | x16 (6.3M) | n16 (6.3M) |
    //   WBUF fp16 weights (9.44M: qkv_t 1.77M | proj_t 0.59M | fc_t 2.36M;
    //     wpr_t 2.36M halves reuses WBUF base after FC1) |
    //   BIG (25.2M union): q16,k16,vT16 (18.9M) + attnb16 (6.3M tail) ;
    //                      t f32 (12.6M head, after q/k dead) ; m16 (whole)
    float* x   = (float*)d_ws;
    float* n   = x + (size_t)MM * DD;
    _Float16* x16  = (_Float16*)(n + (size_t)MM * DD);
    _Float16* n16  = x16 + (size_t)MM * DD;
    _Float16* WBUF = n16 + (size_t)MM * DD;
    _Float16* wq_t = WBUF;                               // 2304x768
    _Float16* wp_t = wq_t + (size_t)2304 * DD;           // 768x768
    _Float16* wf_t = wp_t + (size_t)DD * DD;             // 3072x768
    _Float16* wr_t = WBUF;                               // 768x3072 (reuse)
    _Float16* BIG  = wf_t + (size_t)DFF * DD;
    _Float16* q16  = BIG;
    _Float16* k16  = q16 + (size_t)MM * DD;
    _Float16* vT16 = k16 + (size_t)MM * DD;
    _Float16* attnb16 = vT16 + (size_t)MM * DD;
    float*    t   = (float*)BIG;
    _Float16* m16 = BIG;

    embed_kernel<<<dim3(MM), 256, 0, stream>>>(tokens, we, x, x16);

    for (int l = 0; l < LL; ++l) {
        // Convert wqkv + wproj + wfc (one dispatch, 1152 tiles)
        convw3_kernel<<<dim3(1152), 256, 0, stream>>>(
            wqkv + (size_t)l * DD * 2304, wproj + (size_t)l * DD * DD,
            wfc + (size_t)l * DD * DFF, wq_t, wp_t, wf_t);
        // QKV projection -> fp16 q/k/vT buffers
        gemm_h_kernel<EPI_QKV><<<dim3(2304 / 128, MM / 128), 256, 0, stream>>>(
            x16, wq_t, bqkv + (size_t)l * 2304, nullptr, nullptr,
            q16, k16, vT16, MM, 2304, DD);
        // MFMA flash attention -> fp16 attnb
        attn_kernel<<<dim3(SS / 64, HH, BB), 256, 0, stream>>>(q16, k16, vT16, attnb16);
        // Output projection + residual(x) -> t fp32
        gemm_h_kernel<EPI_BIAS_RES><<<dim3(DD / 128, MM / 128), 256, 0, stream>>>(
            attnb16, wp_t, bproj + (size_t)l * DD,
            x, t, nullptr, nullptr, nullptr, MM, DD, DD);
        // LN1 -> n fp32 + n16
        ln_kernel<<<dim3(MM), 256, 0, stream>>>(t, g1 + (size_t)l * DD,
                                                b1 + (size_t)l * DD, n, n16);
        // FC + GELU -> m16 fp16
        gemm_h_kernel<EPI_BIAS_GELU><<<dim3(DFF / 128, MM / 128), 256, 0, stream>>>(
            n16, wf_t, bfc + (size_t)l * DFF, nullptr, nullptr,
            m16, nullptr, nullptr, MM, DFF, DD);
        // Convert wpr (reuses WBUF base; qkv/proj/fc weights dead now)
        convw_kernel<<<dim3(576), 256, 0, stream>>>(
            wpr + (size_t)l * DFF * DD, wr_t, DFF, DD);
        // FC2 + residual(n) -> x fp32
        gemm_h_kernel<EPI_BIAS_RES><<<dim3(DD / 128, MM / 128), 256, 0, stream>>>(
            m16, wr_t, bpr + (size_t)l * DD,
            n, x, nullptr, nullptr, nullptr, MM, DD, DFF);
        // LN2 (in-place on x; last layer writes d_out, no fp16 mirror needed)
        ln_kernel<<<dim3(MM), 256, 0, stream>>>(x, g2 + (size_t)l * DD,
                                                b2 + (size_t)l * DD,
                                                (l == LL - 1) ? out : x,
                                                (l == LL - 1) ? nullptr : x16);
    }
}

// Round 5
// 3089.125 us; speedup vs baseline: 1.1492x; 1.0522x over previous
//
#include <hip/hip_runtime.h>
#include <math.h>

// Problem constants
#define BB 8
#define SS 512
#define DD 768
#define HH 12
#define LL 12
#define DFF 3072
#define VV 40478
#define MM (BB*SS)   // 4096 rows

typedef _Float16 half8 __attribute__((ext_vector_type(8)));
typedef _Float16 half4 __attribute__((ext_vector_type(4)));
typedef float floatx4 __attribute__((ext_vector_type(4)));

// async global->LDS, 16B per lane, LDS dest = wave-uniform base + lane*16
#define GLDS(gptr, lptr) \
    __builtin_amdgcn_global_load_lds( \
        (const __attribute__((address_space(1))) void*)(gptr), \
        (__attribute__((address_space(3))) void*)(lptr), 16, 0, 0)

// ---------------------------------------------------------------------------
// Embedding: x[b,s,:] = we[tok[b,s],:] + we[V+s,:]  (fp32 + fp16 mirror)
// ---------------------------------------------------------------------------
__global__ __launch_bounds__(256) void embed_kernel(
    const int* __restrict__ tokens, const float* __restrict__ we,
    float* __restrict__ x, _Float16* __restrict__ x16)
{
    int i = blockIdx.x;
    int s = i & (SS - 1);
    int tok = tokens[i];
    const float* wt = we + (size_t)tok * DD;
    const float* wp = we + (size_t)(VV + s) * DD;
    float* xr = x + (size_t)i * DD;
    _Float16* hr = x16 + (size_t)i * DD;
    for (int d = threadIdx.x; d < DD; d += 256) {
        float v = wt[d] + wp[d];
        xr[d] = v;
        hr[d] = (_Float16)v;
    }
}

// ---------------------------------------------------------------------------
// Weight convert: W fp32 [K][N] -> Wt fp16 [N][K] (transpose), 64x64 tiles.
// convw3_kernel: wqkv + wproj + wfc of one layer in a single dispatch.
// convw_kernel: single matrix (used for wpr, overlapping WBUF reuse).
// ---------------------------------------------------------------------------
__device__ __forceinline__ void convw_tile(
    const float* __restrict__ W, _Float16* __restrict__ Wt,
    int K, int N, int n0, int k0)
{
    __shared__ float tile[64][65];
    const int t = threadIdx.x;
    const int c  = t & 63;
    const int r4 = t >> 6;           // 0..3
#pragma unroll
    for (int rr = 0; rr < 64; rr += 4)
        tile[rr + r4][c] = W[(size_t)(k0 + rr + r4) * N + n0 + c];
    __syncthreads();
#pragma unroll
    for (int nn = 0; nn < 64; nn += 4) {
        int n = nn + r4;
        Wt[(size_t)(n0 + n) * K + k0 + c] = (_Float16)tile[c][n];
    }
}

__global__ __launch_bounds__(256) void convw_kernel(
    const float* __restrict__ W, _Float16* __restrict__ Wt, int K, int N)
{
    const int ntx = N >> 6;
    const int b = blockIdx.x;
    convw_tile(W, Wt, K, N, (b % ntx) * 64, (b / ntx) * 64);
}

__global__ __launch_bounds__(256) void convw3_kernel(
    const float* __restrict__ w0, const float* __restrict__ w1,
    const float* __restrict__ w2,
    _Float16* __restrict__ o0, _Float16* __restrict__ o1,
    _Float16* __restrict__ o2)
{
    int b = blockIdx.x;
    const float* W; _Float16* Wt; int N, tb;
    if (b < 432)       { W = w0; Wt = o0; N = 2304; tb = b; }
    else if (b < 576)  { W = w1; Wt = o1; N = 768;  tb = b - 432; }
    else               { W = w2; Wt = o2; N = 3072; tb = b - 576; }
    const int ntx = N >> 6;
    convw_tile(W, Wt, 768, N, (tb % ntx) * 64, (tb / ntx) * 64);
}

// ---------------------------------------------------------------------------
// fp16-MFMA GEMM: A fp16 [M][K], Bt fp16 [N][K]. 128x128 tile, BK=32,
// 256 threads (4 waves, 64x64 each). Both tiles staged with
// global_load_lds width=16 into fragment-order LDS (chunk = tid, linear).
// 3 SEPARATE LDS buffer symbols + fully unrolled 3-phase loop: buffer
// references are compile-time constants, so the waitcnt pass can emit
// PRECISE counted vmcnt before ds_reads instead of a full vmcnt(0) drain
// (runtime-indexed As[cb] forced a drain every iter in rounds 2-4).
// Per phase: vmcnt(8) -> barrier -> ds_read+MFMA -> barrier -> stage next.
// Issue-to-consume distance = 2 phases >= HBM latency. Epilogue 8/4/0.
// XCD-aware bijective block swizzle for A-panel L2 reuse.
// Epilogues: BIAS_RES (fp32 C=acc+bias+resid), BIAS_GELU (fp16 out),
// QKV (fp16 q scaled, k, transposed vT).
// ---------------------------------------------------------------------------
#define EPI_BIAS_RES 1
#define EPI_BIAS_GELU 2
#define EPI_QKV 3

#define STAGE(AS, BS) do { \
    GLDS(aptr0, &AS[wbase]);        GLDS(aptr1, &AS[2048 + wbase]); \
    GLDS(bptr0, &BS[wbase]);        GLDS(bptr1, &BS[2048 + wbase]); \
    aptr0 += 32; aptr1 += 32; bptr0 += 32; bptr1 += 32; \
} while (0)

#define PHASE(AS, BS, VMC) do { \
    asm volatile("s_waitcnt vmcnt(" #VMC ")" ::: "memory"); \
    __builtin_amdgcn_s_barrier(); \
    asm volatile("" ::: "memory"); \
    half8 af[4], bf[4]; \
    _Pragma("unroll") \
    for (int i_ = 0; i_ < 4; ++i_) \
        af[i_] = *(const half8*)&AS[((wm + i_) * 64 + lane) * 8]; \
    _Pragma("unroll") \
    for (int i_ = 0; i_ < 4; ++i_) \
        bf[i_] = *(const half8*)&BS[((wn + i_) * 64 + lane) * 8]; \
    _Pragma("unroll") \
    for (int i_ = 0; i_ < 4; ++i_) \
        _Pragma("unroll") \
        for (int j_ = 0; j_ < 4; ++j_) \
            acc[i_][j_] = __builtin_amdgcn_mfma_f32_16x16x32_f16( \
                af[i_], bf[j_], acc[i_][j_], 0, 0, 0); \
    asm volatile("" ::: "memory"); \
    __builtin_amdgcn_s_barrier(); \
    asm volatile("" ::: "memory"); \
} while (0)

template<int EPI>
__global__ __launch_bounds__(256) void gemm_h_kernel(
    const _Float16* __restrict__ A, const _Float16* __restrict__ Bt,
    const float* __restrict__ bias, const float* __restrict__ resid,
    float* __restrict__ C, _Float16* __restrict__ h16o,
    _Float16* __restrict__ k16o, _Float16* __restrict__ vTo,
    int M, int N, int K)
{
    __shared__ _Float16 As0[4096], As1[4096], As2[4096];
    __shared__ _Float16 Bs0[4096], Bs1[4096], Bs2[4096];

    const int tid  = threadIdx.x;
    const int lane = tid & 63;
    const int wave = tid >> 6;

    // wave-uniform LDS base (halves): lane l lands at +l*16B
    const int wbase = __builtin_amdgcn_readfirstlane(wave << 9);

    // XCD-aware bijective swizzle (all grids are multiples of 8 blocks)
    const int gx  = gridDim.x;
    const int lb  = blockIdx.y * gx + blockIdx.x;
    const int q8  = (gx * gridDim.y) >> 3;
    const int swz = (lb & 7) * q8 + (lb >> 3);
    const int row0 = (swz / gx) * 128, col0 = (swz % gx) * 128;

    // staging: thread's (row, kchunk) chosen so LDS chunk index == tid
    const int srow = ((tid >> 6) << 4) + (tid & 15);   // 0..63
    const int skc  = (tid >> 4) & 3;                   // kchunk 0..3
    const _Float16* aptr0 = A  + (size_t)(row0 + srow) * K      + skc * 8;
    const _Float16* aptr1 = A  + (size_t)(row0 + 64 + srow) * K + skc * 8;
    const _Float16* bptr0 = Bt + (size_t)(col0 + srow) * K      + skc * 8;
    const _Float16* bptr1 = Bt + (size_t)(col0 + 64 + srow) * K + skc * 8;

    const int wm = (wave >> 1) << 2;
    const int wn = (wave & 1) << 2;

    floatx4 acc[4][4] = {};

    const int nk = K >> 5;   // 24 or 96 -- always a multiple of 3

    // prologue: stage tiles 0,1,2 into the three buffers
    STAGE(As0, Bs0);
    STAGE(As1, Bs1);
    STAGE(As2, Bs2);

    // steady state: compute t,t+1,t+2; stage t+3,t+4,t+5
    for (int t = 0; t + 6 <= nk; t += 3) {
        PHASE(As0, Bs0, 8); STAGE(As0, Bs0);
        PHASE(As1, Bs1, 8); STAGE(As1, Bs1);
        PHASE(As2, Bs2, 8); STAGE(As2, Bs2);
    }
    // epilogue: last three tiles, draining 8/4/0
    PHASE(As0, Bs0, 8);
    PHASE(As1, Bs1, 4);
    PHASE(As2, Bs2, 0);

    // Epilogue. C/D layout: col = lane&15, row = (lane>>4)*4 + reg.
    if (EPI == EPI_QKV) {
        const int part = col0 / 768;   // 0=q, 1=k, 2=v (tile never spans parts)
#pragma unroll
        for (int i = 0; i < 4; ++i) {
            int rowb = row0 + ((wm + i) << 4) + ((lane >> 4) << 2);
            int bidx = rowb >> 9;
            int s0   = rowb & 511;
#pragma unroll
            for (int j = 0; j < 4; ++j) {
                int col = col0 + ((wn + j) << 4) + (lane & 15);
                float bsv = bias[col];
                int hh = (col >> 6) % 12;
                int dd = col & 63;
                size_t hb = ((size_t)(bidx * 12 + hh)) << 15;  // *512*64
                if (part == 0) {
#pragma unroll
                    for (int r = 0; r < 4; ++r)
                        h16o[hb + (size_t)(s0 + r) * 64 + dd] =
                            (_Float16)((acc[i][j][r] + bsv) * 0.125f);
                } else if (part == 1) {
#pragma unroll
                    for (int r = 0; r < 4; ++r)
                        k16o[hb + (size_t)(s0 + r) * 64 + dd] =
                            (_Float16)(acc[i][j][r] + bsv);
                } else {
                    half4 pk;
#pragma unroll
                    for (int r = 0; r < 4; ++r)
                        pk[r] = (_Float16)(acc[i][j][r] + bsv);
                    *(half4*)&vTo[hb + (size_t)dd * 512 + s0] = pk;
                }
            }
        }
    } else {
#pragma unroll
        for (int i = 0; i < 4; ++i) {
            int rowb = row0 + ((wm + i) << 4) + ((lane >> 4) << 2);
#pragma unroll
            for (int j = 0; j < 4; ++j) {
                int col = col0 + ((wn + j) << 4) + (lane & 15);
                float bsv = bias[col];
#pragma unroll
                for (int r = 0; r < 4; ++r) {
                    int row = rowb + r;
                    float v = acc[i][j][r] + bsv;
                    if (EPI == EPI_BIAS_RES) {
                        v += resid[(size_t)row * N + col];
                        C[(size_t)row * N + col] = v;
                    }
                    if (EPI == EPI_BIAS_GELU) {
                        float u = v;
                        v = 0.5f * u * (1.0f + tanhf(0.7978845608028654f * (u + 0.044715f * u * u * u)));
                        h16o[(size_t)row * N + col] = (_Float16)v;
                    }
                }
            }
        }
    }
}

// ---------------------------------------------------------------------------
// MFMA flash attention. Block = (q-tile 64, head, batch); 4 waves x 16 q-rows.
// q16 pre-scaled by 1/8. k16: [b,h,s,d]. vT16: [b,h,d,s]. Out fp16 attnb16.
// LDS strides padded (72 f16 / 68 f32) -> all b128 patterns conflict-free.
// ---------------------------------------------------------------------------
__global__ __launch_bounds__(256) void attn_kernel(
    const _Float16* __restrict__ q16, const _Float16* __restrict__ k16,
    const _Float16* __restrict__ vT16, _Float16* __restrict__ attnb)
{
    const int qt = 7 - blockIdx.x;   // biggest q-tiles first
    const int h  = blockIdx.y;
    const int b  = blockIdx.z;
    const int tid  = threadIdx.x;
    const int lane = tid & 63;
    const int wave = tid >> 6;
    const int quad = lane >> 4;
    const int l15  = lane & 15;
    const int wq   = wave << 4;      // wave's q-row base in tile

    __shared__ _Float16 Kt[64 * 72];
    __shared__ _Float16 Vt[64 * 72];   // [d][key]
    __shared__ _Float16 Ps[64 * 72];
    __shared__ float    Ss[64 * 68];
    __shared__ float mS[64], lS[64], aS[64];

    const size_t headbase = ((size_t)(b * HH + h)) << 15;   // *512*64
    const int q0 = qt * 64;

    // Q fragments in registers for the whole kernel (A-operand layout)
    half8 qf0, qf1;
    {
        const _Float16* qp = q16 + headbase + (size_t)(q0 + wq + l15) * 64 + quad * 8;
        qf0 = *(const half8*)qp;
        qf1 = *(const half8*)(qp + 32);
    }
    if (tid < 64) { mS[tid] = -1e30f; lS[tid] = 0.f; }

    floatx4 o[4] = {};

    for (int kt = 0; kt <= qt; ++kt) {
        // --- stage K tile [key][d] and V^T tile [d][key] ---
        {
            int r = tid >> 2;
            int c = (tid & 3) << 4;
            const _Float16* kp = k16 + headbase + (size_t)(kt * 64 + r) * 64 + c;
            half8 k0 = *(const half8*)kp;
            half8 k1 = *(const half8*)(kp + 8);
            const _Float16* vp = vT16 + headbase + (size_t)r * 512 + kt * 64 + c;
            half8 v0 = *(const half8*)vp;
            half8 v1 = *(const half8*)(vp + 8);
            __syncthreads();   // previous iteration fully consumed LDS
            *(half8*)&Kt[r * 72 + c]     = k0;
            *(half8*)&Kt[r * 72 + c + 8] = k1;
            *(half8*)&Vt[r * 72 + c]     = v0;
            *(half8*)&Vt[r * 72 + c + 8] = v1;
        }
        __syncthreads();

        // --- S = Q K^T : 4 key-subtiles x 2 MFMA ---
        floatx4 s4[4];
#pragma unroll
        for (int t4 = 0; t4 < 4; ++t4) {
            half8 kf0 = *(const half8*)&Kt[(t4 * 16 + l15) * 72 + quad * 8];
            half8 kf1 = *(const half8*)&Kt[(t4 * 16 + l15) * 72 + quad * 8 + 32];
            floatx4 a = {};
            a = __builtin_amdgcn_mfma_f32_16x16x32_f16(qf0, kf0, a, 0, 0, 0);
            a = __builtin_amdgcn_mfma_f32_16x16x32_f16(qf1, kf1, a, 0, 0, 0);
            s4[t4] = a;
        }

        // --- causal mask on diagonal tile ---
        if (kt == qt) {
#pragma unroll
            for (int t4 = 0; t4 < 4; ++t4) {
                int kc = t4 * 16 + l15;
#pragma unroll
                for (int r = 0; r < 4; ++r)
                    if (kc > wq + quad * 4 + r) s4[t4][r] = -1e30f;
            }
        }

        // --- scores to LDS (C-layout scatter, conflict-free) ---
#pragma unroll
        for (int t4 = 0; t4 < 4; ++t4)
#pragma unroll
            for (int r = 0; r < 4; ++r)
                Ss[(wq + quad * 4 + r) * 68 + t4 * 16 + l15] = s4[t4][r];
        __syncthreads();

        // --- online softmax: 4 lanes per row, 16 cols each ---
        {
            int rr = tid >> 2, sub = tid & 3;
            float4 p0 = *(const float4*)&Ss[rr * 68 + sub * 16 + 0];
            float4 p1 = *(const float4*)&Ss[rr * 68 + sub * 16 + 4];
            float4 p2 = *(const float4*)&Ss[rr * 68 + sub * 16 + 8];
            float4 p3 = *(const float4*)&Ss[rr * 68 + sub * 16 + 12];
            float tmax = fmaxf(fmaxf(fmaxf(p0.x, p0.y), fmaxf(p0.z, p0.w)),
                         fmaxf(fmaxf(fmaxf(p1.x, p1.y), fmaxf(p1.z, p1.w)),
                         fmaxf(fmaxf(fmaxf(p2.x, p2.y), fmaxf(p2.z, p2.w)),
                               fmaxf(fmaxf(p3.x, p3.y), fmaxf(p3.z, p3.w)))));
            tmax = fmaxf(tmax, __shfl_xor(tmax, 1));
            tmax = fmaxf(tmax, __shfl_xor(tmax, 2));
            float mold = mS[rr];
            float mnew = fmaxf(mold, tmax);
            p0.x = __expf(p0.x - mnew); p0.y = __expf(p0.y - mnew);
            p0.z = __expf(p0.z - mnew); p0.w = __expf(p0.w - mnew);
            p1.x = __expf(p1.x - mnew); p1.y = __expf(p1.y - mnew);
            p1.z = __expf(p1.z - mnew); p1.w = __expf(p1.w - mnew);
            p2.x = __expf(p2.x - mnew); p2.y = __expf(p2.y - mnew);
            p2.z = __expf(p2.z - mnew); p2.w = __expf(p2.w - mnew);
            p3.x = __expf(p3.x - mnew); p3.y = __expf(p3.y - mnew);
            p3.z = __expf(p3.z - mnew); p3.w = __expf(p3.w - mnew);
            float sum = p0.x + p0.y + p0.z + p0.w + p1.x + p1.y + p1.z + p1.w
                      + p2.x + p2.y + p2.z + p2.w + p3.x + p3.y + p3.z + p3.w;
            sum += __shfl_xor(sum, 1);
            sum += __shfl_xor(sum, 2);
            half8 ph0, ph1;
            ph0[0] = (_Float16)p0.x; ph0[1] = (_Float16)p0.y;
            ph0[2] = (_Float16)p0.z; ph0[3] = (_Float16)p0.w;
            ph0[4] = (_Float16)p1.x; ph0[5] = (_Float16)p1.y;
            ph0[6] = (_Float16)p1.z; ph0[7] = (_Float16)p1.w;
            ph1[0] = (_Float16)p2.x; ph1[1] = (_Float16)p2.y;
            ph1[2] = (_Float16)p2.z; ph1[3] = (_Float16)p2.w;
            ph1[4] = (_Float16)p3.x; ph1[5] = (_Float16)p3.y;
            ph1[6] = (_Float16)p3.z; ph1[7] = (_Float16)p3.w;
            *(half8*)&Ps[rr * 72 + sub * 16]     = ph0;
            *(half8*)&Ps[rr * 72 + sub * 16 + 8] = ph1;
            if (sub == 0) {
                float al = __expf(mold - mnew);
                aS[rr] = al;
                mS[rr] = mnew;
                lS[rr] = lS[rr] * al + sum;
            }
        }
        __syncthreads();

        // --- O = O*alpha + P @ V ---
        {
            float al[4];
#pragma unroll
            for (int r = 0; r < 4; ++r) al[r] = aS[wq + quad * 4 + r];
#pragma unroll
            for (int dt = 0; dt < 4; ++dt)
#pragma unroll
                for (int r = 0; r < 4; ++r) o[dt][r] *= al[r];

            half8 pf0 = *(const half8*)&Ps[(wq + l15) * 72 + quad * 8];
            half8 pf1 = *(const half8*)&Ps[(wq + l15) * 72 + quad * 8 + 32];
#pragma unroll
            for (int dt = 0; dt < 4; ++dt) {
                half8 vf0 = *(const half8*)&Vt[(dt * 16 + l15) * 72 + quad * 8];
                half8 vf1 = *(const half8*)&Vt[(dt * 16 + l15) * 72 + quad * 8 + 32];
                o[dt] = __builtin_amdgcn_mfma_f32_16x16x32_f16(pf0, vf0, o[dt], 0, 0, 0);
                o[dt] = __builtin_amdgcn_mfma_f32_16x16x32_f16(pf1, vf1, o[dt], 0, 0, 0);
            }
        }
    }

    // --- finalize: O / l, write fp16 [token][768] ---
    float inv[4];
#pragma unroll
    for (int r = 0; r < 4; ++r) inv[r] = 1.0f / lS[wq + quad * 4 + r];
#pragma unroll
    for (int dt = 0; dt < 4; ++dt) {
        int col = h * 64 + dt * 16 + l15;
#pragma unroll
        for (int r = 0; r < 4; ++r) {
            int row = b * SS + q0 + wq + quad * 4 + r;
            attnb[(size_t)row * DD + col] = (_Float16)(o[dt][r] * inv[r]);
        }
    }
}

// ---------------------------------------------------------------------------
// LayerNorm over last dim (768). One block per row; in-place safe.
// Optional fp16 mirror output for next GEMM's A operand.
// ---------------------------------------------------------------------------
__global__ __launch_bounds__(256) void ln_kernel(
    const float* __restrict__ in, const float* __restrict__ gam,
    const float* __restrict__ bet, float* __restrict__ out,
    _Float16* __restrict__ out16)
{
    int row = blockIdx.x;
    int tid = threadIdx.x;
    const float* p = in + (size_t)row * DD;
    float v0 = p[tid], v1 = p[tid + 256], v2 = p[tid + 512];

    __shared__ float red[256];
    red[tid] = v0 + v1 + v2;
    __syncthreads();
    for (int off = 128; off > 0; off >>= 1) {
        if (tid < off) red[tid] += red[tid + off];
        __syncthreads();
    }
    float mean = red[0] * (1.0f / DD);
    __syncthreads();

    float d0 = v0 - mean, d1 = v1 - mean, d2 = v2 - mean;
    red[tid] = d0 * d0 + d1 * d1 + d2 * d2;
    __syncthreads();
    for (int off = 128; off > 0; off >>= 1) {
        if (tid < off) red[tid] += red[tid + off];
        __syncthreads();
    }
    float rstd = rsqrtf(red[0] * (1.0f / DD) + 1e-5f);

    float* o = out + (size_t)row * DD;
    float r0 = gam[tid]       * (d0 * rstd) + bet[tid];
    float r1 = gam[tid + 256] * (d1 * rstd) + bet[tid + 256];
    float r2 = gam[tid + 512] * (d2 * rstd) + bet[tid + 512];
    o[tid] = r0; o[tid + 256] = r1; o[tid + 512] = r2;
    if (out16) {
        _Float16* oh = out16 + (size_t)row * DD;
        oh[tid] = (_Float16)r0; oh[tid + 256] = (_Float16)r1; oh[tid + 512] = (_Float16)r2;
    }
}

// ---------------------------------------------------------------------------
extern "C" void kernel_launch(void* const* d_in, const int* in_sizes, int n_in,
                              void* d_out, int out_size, void* d_ws, size_t ws_size,
                              hipStream_t stream)
{
    const int*   tokens = (const int*)d_in[0];
    const float* we     = (const float*)d_in[1];
    const float* wqkv   = (const float*)d_in[2];
    const float* bqkv   = (const float*)d_in[3];
    const float* wproj  = (const float*)d_in[4];
    const float* bproj  = (const float*)d_in[5];
    const float* g1     = (const float*)d_in[6];
    const float* b1     = (const float*)d_in[7];
    const float* wfc    = (const float*)d_in[8];
    const float* bfc    = (const float*)d_in[9];
    const float* wpr    = (const float*)d_in[10];
    const float* bpr    = (const float*)d_in[11];
    const float* g2     = (const float*)d_in[12];
    const float* b2     = (const float*)d_in[13];
    float* out = (float*)d_out;

    // Workspace (72.4 MB):
    //   x f32 (12.6M) | n f32 (12.6M) | x16 (6.3M) | n16 (6.3M) |
    //   WBUF fp16 weights (9.44M: qkv_t 1.77M | proj_t 0.59M | fc_t 2.36M;
    //     wpr_t 2.36M halves reuses WBUF base after FC1) |
    //   BIG (25.2M union): q16,k16,vT16 (18.9M) + attnb16 (6.3M tail) ;
    //                      t f32 (12.6M head, after q/k dead) ; m16 (whole)
    float* x   = (float*)d_ws;
    float* n   = x + (size_t)MM * DD;
    _Float16* x16  = (_Float16*)(n + (size_t)MM * DD);
    _Float16* n16  = x16 + (size_t)MM * DD;
    _Float16* WBUF = n16 + (size_t)MM * DD;
    _Float16* wq_t = WBUF;                               // 2304x768
    _Float16* wp_t = wq_t + (size_t)2304 * DD;           // 768x768
    _Float16* wf_t = wp_t + (size_t)DD * DD;             // 3072x768
    _Float16* wr_t = WBUF;                               // 768x3072 (reuse)
    _Float16* BIG  = wf_t + (size_t)DFF * DD;
    _Float16* q16  = BIG;
    _Float16* k16  = q16 + (size_t)MM * DD;
    _Float16* vT16 = k16 + (size_t)MM * DD;
    _Float16* attnb16 = vT16 + (size_t)MM * DD;
    float*    t   = (float*)BIG;
    _Float16* m16 = BIG;

    embed_kernel<<<dim3(MM), 256, 0, stream>>>(tokens, we, x, x16);

    for (int l = 0; l < LL; ++l) {
        // Convert wqkv + wproj + wfc (one dispatch, 1152 tiles)
        convw3_kernel<<<dim3(1152), 256, 0, stream>>>(
            wqkv + (size_t)l * DD * 2304, wproj + (size_t)l * DD * DD,
            wfc + (size_t)l * DD * DFF, wq_t, wp_t, wf_t);
        // QKV projection -> fp16 q/k/vT buffers
        gemm_h_kernel<EPI_QKV><<<dim3(2304 / 128, MM / 128), 256, 0, stream>>>(
            x16, wq_t, bqkv + (size_t)l * 2304, nullptr, nullptr,
            q16, k16, vT16, MM, 2304, DD);
        // MFMA flash attention -> fp16 attnb
        attn_kernel<<<dim3(SS / 64, HH, BB), 256, 0, stream>>>(q16, k16, vT16, attnb16);
        // Output projection + residual(x) -> t fp32
        gemm_h_kernel<EPI_BIAS_RES><<<dim3(DD / 128, MM / 128), 256, 0, stream>>>(
            attnb16, wp_t, bproj + (size_t)l * DD,
            x, t, nullptr, nullptr, nullptr, MM, DD, DD);
        // LN1 -> n fp32 + n16
        ln_kernel<<<dim3(MM), 256, 0, stream>>>(t, g1 + (size_t)l * DD,
                                                b1 + (size_t)l * DD, n, n16);
        // FC + GELU -> m16 fp16
        gemm_h_kernel<EPI_BIAS_GELU><<<dim3(DFF / 128, MM / 128), 256, 0, stream>>>(
            n16, wf_t, bfc + (size_t)l * DFF, nullptr, nullptr,
            m16, nullptr, nullptr, MM, DFF, DD);
        // Convert wpr (reuses WBUF base; qkv/proj/fc weights dead now)
        convw_kernel<<<dim3(576), 256, 0, stream>>>(
            wpr + (size_t)l * DFF * DD, wr_t, DFF, DD);
        // FC2 + residual(n) -> x fp32
        gemm_h_kernel<EPI_BIAS_RES><<<dim3(DD / 128, MM / 128), 256, 0, stream>>>(
            m16, wr_t, bpr + (size_t)l * DD,
            n, x, nullptr, nullptr, nullptr, MM, DD, DFF);
        // LN2 (in-place on x; last layer writes d_out, no fp16 mirror needed)
        ln_kernel<<<dim3(MM), 256, 0, stream>>>(x, g2 + (size_t)l * DD,
                                                b2 + (size_t)l * DD,
                                                (l == LL - 1) ? out : x,
                                                (l == LL - 1) ? nullptr : x16);
    }
}